// Round 13
// baseline (429.012 us; speedup 1.0000x reference)
//
#include <hip/hip_runtime.h>

// MACE layer v13: v12 (passed, 416.5 us) + ONE change: node_mfma
// __launch_bounds__(256,2) -> (256,4) (16 waves/CU) to hide gather latency.
// Everything else byte-identical to v12.

typedef __attribute__((ext_vector_type(8))) short bf16x8;
typedef __attribute__((ext_vector_type(4))) float f32x4;

constexpr int kN = 50000;
constexpr int kE = 400000;
constexpr int kS = 10;
constexpr int kTilesMax = 3150;

// ws layout (bytes) — v6's
constexpr size_t kOffM    = 0;           // kE*256 ushort = 204,800,000
constexpr size_t kOffCnt  = 204800000;   // kN int
constexpr size_t kOffCnt2 = 205000000;   // 16 int
constexpr size_t kOffOff  = 205000064;   // kN+1 int
constexpr size_t kOffOff2 = 205200128;   // 16 int
constexpr size_t kOffCur  = 205200192;   // kN int
constexpr size_t kOffCur2 = 205400192;   // 16 int
constexpr size_t kOffPos  = 205400256;   // kE int (local rank within segment)
constexpr size_t kOffNidx = 207000256;   // kTilesMax*16 int
constexpr size_t kOffWlT0 = 207201856;   // 4096 ushort each
constexpr size_t kOffWlT1 = 207210048;
constexpr size_t kOffWpT0 = 207218240;
constexpr size_t kOffWpT1 = 207226432;
constexpr size_t kOffWrT0 = 207234624;   // 10*4096 ushort
constexpr size_t kOffWrT1 = 207316544;   // end 207,398,464

__device__ __forceinline__ float silu_f(float x) {
    float t = __expf(-x);
    return x / (1.0f + t);
}
// manual RNE f32->bf16 (edge path — do NOT replace with cvt_pk asm; v10 NaN)
__device__ __forceinline__ unsigned short f2bf(float f) {
    unsigned u = __float_as_uint(f);
    unsigned r = (u + 0x7FFFu + ((u >> 16) & 1u)) >> 16;
    return (unsigned short)r;
}
// cvt_pk helpers (node path only — proven there)
__device__ __forceinline__ unsigned cvt_pk_bf16(float lo, float hi) {
    unsigned r;
    asm("v_cvt_pk_bf16_f32 %0, %1, %2" : "=v"(r) : "v"(lo), "v"(hi));
    return r;
}
__device__ __forceinline__ unsigned short f2bf1(float x) {
    return (unsigned short)cvt_pk_bf16(x, 0.f);
}
__device__ __forceinline__ float bf2f(unsigned short b) {
    return __uint_as_float(((unsigned)b) << 16);
}
__device__ __forceinline__ int swz128(int row, int byteoff) {
    return row * 128 + (byteoff ^ ((row & 7) << 4));
}

// ---------------------------------------------------------------------------
// prep: edge hist stores local rank -> pos; species hist (LDS-agg); weights
// ---------------------------------------------------------------------------
__global__ __launch_bounds__(256)
void prep_kernel(const int* __restrict__ rcv, const int* __restrict__ spc,
                 const float* __restrict__ Wl0, const float* __restrict__ Wl1,
                 const float* __restrict__ Wp0, const float* __restrict__ Wp1,
                 const float* __restrict__ Wres0, const float* __restrict__ Wres1,
                 int* __restrict__ cnt, int* __restrict__ cnt2,
                 int* __restrict__ pos,
                 unsigned short* __restrict__ WlT0, unsigned short* __restrict__ WlT1,
                 unsigned short* __restrict__ WpT0, unsigned short* __restrict__ WpT1,
                 unsigned short* __restrict__ WrT0, unsigned short* __restrict__ WrT1)
{
    const int tid = threadIdx.x;
    const int gtid = blockIdx.x * 256 + tid;
    const int gstride = gridDim.x * 256;

    for (int i = gtid; i < kE; i += gstride) pos[i] = atomicAdd(&cnt[rcv[i]], 1);

    __shared__ int lh[kS];
    for (int base = blockIdx.x * 256; base < kN; base += gstride) {
        if (tid < kS) lh[tid] = 0;
        __syncthreads();
        int node = base + tid;
        if (node < kN) atomicAdd(&lh[spc[node]], 1);
        __syncthreads();
        if (tid < kS && lh[tid]) atomicAdd(&cnt2[tid], lh[tid]);
        __syncthreads();
    }

    for (int i3 = gtid; i3 < 16384 + 81920; i3 += gstride) {
        if (i3 < 16384) {
            int w = i3 >> 12, r = i3 & 4095, k = r >> 6, n = r & 63;
            const float* src = (w == 0) ? Wl0 : (w == 1) ? Wl1 : (w == 2) ? Wp0 : Wp1;
            unsigned short* dst = (w == 0) ? WlT0 : (w == 1) ? WlT1 : (w == 2) ? WpT0 : WpT1;
            dst[swz128(n, 2 * k) >> 1] = f2bf(src[r]);
        } else {
            int i4 = i3 - 16384;
            int w = i4 / 40960;
            int r5 = i4 - w * 40960;                 // s*4096 + c*64 + d
            int s = r5 >> 12, r = r5 & 4095, k = r >> 6, n = r & 63;
            const float* src = w ? Wres1 : Wres0;
            unsigned short* dst = w ? WrT1 : WrT0;
            dst[(s << 12) + (swz128(n, 2 * k) >> 1)] = f2bf(src[r5]);
        }
    }
}

// ---------------------------------------------------------------------------
__global__ __launch_bounds__(1024)
void scan_kernel(const int* __restrict__ cnt, int* __restrict__ off,
                 int* __restrict__ cur,
                 const int* __restrict__ cnt2, int* __restrict__ off2,
                 int* __restrict__ cur2)
{
    __shared__ int wred[16];
    const int tid = threadIdx.x;
    const int lane = tid & 63;
    const int wv = tid >> 6;
    const int CH = 49;
    const int b = tid * CH;
    int s = 0;
    for (int i = 0; i < CH; ++i) {
        int idx = b + i;
        if (idx < kN) s += cnt[idx];
    }
    int incl = s;
    for (int d = 1; d < 64; d <<= 1) {
        int t = __shfl_up(incl, d, 64);
        if (lane >= d) incl += t;
    }
    if (lane == 63) wred[wv] = incl;
    __syncthreads();
    if (tid < 16) {
        int o = wred[tid];
        int v = o;
        for (int d = 1; d < 16; d <<= 1) {
            int t = __shfl_up(v, d, 64);
            if (tid >= d) v += t;
        }
        wred[tid] = v - o;
    }
    __syncthreads();
    int run = wred[wv] + (incl - s);
    for (int i = 0; i < CH; ++i) {
        int idx = b + i;
        if (idx < kN) {
            int c = cnt[idx];
            off[idx] = run;
            cur[idx] = run;
            run += c;
        }
    }
    if (tid == 0) {
        off[kN] = kE;
        int base = 0;
        for (int sp = 0; sp < kS; ++sp) {
            off2[sp] = base;
            cur2[sp] = base;
            base += (cnt2[sp] + 15) & ~15;
        }
        off2[kS] = base;
    }
}

// ---------------------------------------------------------------------------
__global__ __launch_bounds__(256)
void rank_kernel(const int* __restrict__ spc,
                 int* __restrict__ cur2, int* __restrict__ nidx)
{
    const int tid = threadIdx.x;
    const int gstride = gridDim.x * 256;

    __shared__ int lh[kS];
    __shared__ int gbase[kS];
    for (int base = blockIdx.x * 256; base < kN; base += gstride) {
        if (tid < kS) lh[tid] = 0;
        __syncthreads();
        const int node = base + tid;
        int s = -1, lr = 0;
        if (node < kN) {
            s = spc[node];
            lr = atomicAdd(&lh[s], 1);
        }
        __syncthreads();
        if (tid < kS) gbase[tid] = lh[tid] ? atomicAdd(&cur2[tid], lh[tid]) : 0;
        __syncthreads();
        if (node < kN) nidx[gbase[s] + lr] = node;
        __syncthreads();
    }
}

// ---------------------------------------------------------------------------
// edge_mfma (v12, unchanged). 512 thr (8 waves), 16 edges/wave.
// ---------------------------------------------------------------------------
__global__ __launch_bounds__(512, 1)
void edge_mfma(const float* __restrict__ ev,
               const float* __restrict__ nf,
               const float* __restrict__ rad,
               const int* __restrict__ snd,
               const int* __restrict__ rcv,
               const int* __restrict__ off,
               const int* __restrict__ pos,
               const float* __restrict__ W1,
               const float* __restrict__ W2,
               const float* __restrict__ W3,
               unsigned short* __restrict__ mq)
{
    __shared__ unsigned short W2T[64 * 64];
    __shared__ unsigned short W3T[256 * 64];
    __shared__ unsigned short h1s[8][16 * 64];
    __shared__ unsigned short h2s[8][16 * 64];
    __shared__ unsigned short wTs[8][256 * 20];

    const int tid = threadIdx.x;
    for (int i = tid; i < 64 * 64; i += 512) {
        int k = i >> 6, n = i & 63;
        W2T[swz128(n, 2 * k) >> 1] = f2bf(W2[i]);
    }
    for (int i = tid; i < 256 * 64; i += 512) {
        int k = i >> 8, n = i & 255;
        W3T[swz128(n, 2 * k) >> 1] = f2bf(W3[i]);
    }
    __syncthreads();

    const int lane = tid & 63;
    const int wvi = tid >> 6;
    const int l15 = lane & 15;
    const int g = lane >> 4;

    float w1r[8];
#pragma unroll
    for (int r = 0; r < 8; ++r) w1r[r] = W1[(r << 6) | lane];

    unsigned short* h1w = h1s[wvi];
    unsigned short* h2w = h2s[wvi];
    unsigned short* wTw = wTs[wvi];

    for (int t = blockIdx.x; t < kE / 128; t += gridDim.x) {
        const int et = t * 128 + wvi * 16;

        for (int e = 0; e < 16; ++e) {
            const float4 ra = *(const float4*)&rad[(size_t)(et + e) * 8];
            const float4 rb = *(const float4*)&rad[(size_t)(et + e) * 8 + 4];
            float acc = ra.x * w1r[0] + ra.y * w1r[1] + ra.z * w1r[2] + ra.w * w1r[3]
                      + rb.x * w1r[4] + rb.y * w1r[5] + rb.z * w1r[6] + rb.w * w1r[7];
            h1w[swz128(e, 2 * lane) >> 1] = f2bf(silu_f(acc));
        }
        __builtin_amdgcn_wave_barrier();

        bf16x8 a0 = *(const bf16x8*)&h1w[swz128(l15, g * 16) >> 1];
        bf16x8 a1 = *(const bf16x8*)&h1w[swz128(l15, 64 + g * 16) >> 1];

#pragma unroll
        for (int n0 = 0; n0 < 64; n0 += 16) {
            const int n = n0 + l15;
            bf16x8 b0 = *(const bf16x8*)&W2T[swz128(n, g * 16) >> 1];
            bf16x8 b1 = *(const bf16x8*)&W2T[swz128(n, 64 + g * 16) >> 1];
            f32x4 acc = {0.f, 0.f, 0.f, 0.f};
            acc = __builtin_amdgcn_mfma_f32_16x16x32_bf16(a0, b0, acc, 0, 0, 0);
            acc = __builtin_amdgcn_mfma_f32_16x16x32_bf16(a1, b1, acc, 0, 0, 0);
#pragma unroll
            for (int r = 0; r < 4; ++r) {
                int e2 = g * 4 + r;
                h2w[swz128(e2, 2 * n) >> 1] = f2bf(silu_f(acc[r]));
            }
        }
        __builtin_amdgcn_wave_barrier();

        bf16x8 c0 = *(const bf16x8*)&h2w[swz128(l15, g * 16) >> 1];
        bf16x8 c1 = *(const bf16x8*)&h2w[swz128(l15, 64 + g * 16) >> 1];
#pragma unroll
        for (int m0 = 0; m0 < 16; ++m0) {
            const int nrow = m0 * 16 + l15;
            bf16x8 wa0 = *(const bf16x8*)&W3T[swz128(nrow, g * 16) >> 1];
            bf16x8 wa1 = *(const bf16x8*)&W3T[swz128(nrow, 64 + g * 16) >> 1];
            f32x4 acc = {0.f, 0.f, 0.f, 0.f};
            acc = __builtin_amdgcn_mfma_f32_16x16x32_bf16(wa0, c0, acc, 0, 0, 0);
            acc = __builtin_amdgcn_mfma_f32_16x16x32_bf16(wa1, c1, acc, 0, 0, 0);
#pragma unroll
            for (int r = 0; r < 4; ++r) {
                int nn = m0 * 16 + g * 4 + r;
                wTw[nn * 20 + l15] = f2bf(acc[r]);
            }
        }
        __builtin_amdgcn_wave_barrier();

        const int c = lane;
#pragma unroll
        for (int grp = 0; grp < 4; ++grp) {
            ushort4 qa[4];
#pragma unroll
            for (int k = 0; k < 4; ++k)
                qa[k] = *(const ushort4*)&wTw[(k * 64 + c) * 20 + grp * 4];
            const unsigned short* qp = (const unsigned short*)qa;
#pragma unroll
            for (int e = 0; e < 4; ++e) {
                const int eid = et + grp * 4 + e;
                const int sid = snd[eid];
                const int p = off[rcv[eid]] + pos[eid];
                const float ex = ev[(size_t)eid * 3 + 0];
                const float ey = ev[(size_t)eid * 3 + 1];
                const float ez = ev[(size_t)eid * 3 + 2];
                const float ri = rsqrtf(ex * ex + ey * ey + ez * ez + 1e-12f);
                const float y0 = 1.7320508075688772f * ex * ri;
                const float y1 = 1.7320508075688772f * ey * ri;
                const float y2 = 1.7320508075688772f * ez * ri;
                const float4 xv = *(const float4*)&nf[(((size_t)sid << 6) | c) << 2];
                const float w0 = bf2f(qp[0 * 4 + e]);
                const float w1 = bf2f(qp[1 * 4 + e]);
                const float w2v = bf2f(qp[2 * 4 + e]);
                const float w3v = bf2f(qp[3 * 4 + e]);
                const float dot1 = xv.y * y0 + xv.z * y1 + xv.w * y2;
                const float m0v = w0 * xv.x + w1 * dot1;
                const float t2 = w2v * xv.x;
                ushort4 q;
                q.x = f2bf(m0v);
                q.y = f2bf(t2 * y0 + w3v * xv.y);
                q.z = f2bf(t2 * y1 + w3v * xv.z);
                q.w = f2bf(t2 * y2 + w3v * xv.w);
                *(ushort4*)&mq[((size_t)p << 8) + (c << 2)] = q;
            }
        }
        __builtin_amdgcn_wave_barrier();
    }
}

// ---------------------------------------------------------------------------
// node_mfma (v12 + launch_bounds (256,4)): block (4 waves) per 16-node tile;
// hi/lo slab, 4-deep gather ILP.
// ---------------------------------------------------------------------------
__global__ __launch_bounds__(256, 4)
void node_mfma(const float* __restrict__ nf, const int* __restrict__ spc,
               const unsigned short* __restrict__ WlT0, const unsigned short* __restrict__ WlT1,
               const unsigned short* __restrict__ WpT0, const unsigned short* __restrict__ WpT1,
               const unsigned short* __restrict__ WrT0, const unsigned short* __restrict__ WrT1,
               const float* __restrict__ Wsc0, const float* __restrict__ Wsc1,
               const float* __restrict__ Wrd,
               const unsigned short* __restrict__ m, const int* __restrict__ off,
               const int* __restrict__ nidx,
               float* __restrict__ out0, float* __restrict__ outF)
{
    __shared__ unsigned short slab[8][1024];   // planes 0-3 hi, 4-7 lo (16 KB)
    __shared__ float roS[4][16];

    const int tid = threadIdx.x;
    const int lane = tid & 63;
    const int wvi = tid >> 6;
    const int l15 = lane & 15;
    const int g = lane >> 4;
    const int tb = (int)blockIdx.x << 4;

    const int c = lane;
    for (int e4 = 0; e4 < 4; ++e4) {
        const int e = wvi * 4 + e4;
        const int node = nidx[tb + e];
        float ax = 0.f, ay = 0.f, az = 0.f, aw = 0.f;
        if (node >= 0) {
            const int beg = off[node], end = off[node + 1];
            int i = beg;
            for (; i + 4 <= end; i += 4) {
                const ushort4 q0 = *(const ushort4*)&m[((size_t)(i + 0) << 8) + (c << 2)];
                const ushort4 q1 = *(const ushort4*)&m[((size_t)(i + 1) << 8) + (c << 2)];
                const ushort4 q2 = *(const ushort4*)&m[((size_t)(i + 2) << 8) + (c << 2)];
                const ushort4 q3 = *(const ushort4*)&m[((size_t)(i + 3) << 8) + (c << 2)];
                ax += (bf2f(q0.x) + bf2f(q1.x)) + (bf2f(q2.x) + bf2f(q3.x));
                ay += (bf2f(q0.y) + bf2f(q1.y)) + (bf2f(q2.y) + bf2f(q3.y));
                az += (bf2f(q0.z) + bf2f(q1.z)) + (bf2f(q2.z) + bf2f(q3.z));
                aw += (bf2f(q0.w) + bf2f(q1.w)) + (bf2f(q2.w) + bf2f(q3.w));
            }
            for (; i < end; ++i) {
                const ushort4 q = *(const ushort4*)&m[((size_t)i << 8) + (c << 2)];
                ax += bf2f(q.x); ay += bf2f(q.y); az += bf2f(q.z); aw += bf2f(q.w);
            }
        }
        const float vv[4] = {ax * 0.125f, ay * 0.125f, az * 0.125f, aw * 0.125f};
        const int o = swz128(e, 2 * c) >> 1;
#pragma unroll
        for (int p = 0; p < 4; ++p) {
            const unsigned short hi = f2bf1(vv[p]);
            slab[p][o] = hi;
            slab[4 + p][o] = f2bf1(vv[p] - bf2f(hi));
        }
    }
    __syncthreads();

    const int n0 = nidx[tb];
    if (n0 < 0) return;
    const int s = spc[n0];

    bf16x8 aF[8][2];
#pragma unroll
    for (int p = 0; p < 8; ++p) {
        aF[p][0] = *(const bf16x8*)&slab[p][swz128(l15, g * 16) >> 1];
        aF[p][1] = *(const bf16x8*)&slab[p][swz128(l15, 64 + g * 16) >> 1];
    }
    __syncthreads();

    const int d = l15 + 16 * wvi;
    {
        bf16x8 bl0a = *(const bf16x8*)&WlT0[swz128(d, g * 16) >> 1];
        bf16x8 bl0b = *(const bf16x8*)&WlT0[swz128(d, 64 + g * 16) >> 1];
        bf16x8 bl1a = *(const bf16x8*)&WlT1[swz128(d, g * 16) >> 1];
        bf16x8 bl1b = *(const bf16x8*)&WlT1[swz128(d, 64 + g * 16) >> 1];
        f32x4 A0v = {0.f, 0.f, 0.f, 0.f};
        f32x4 Axv = {0.f, 0.f, 0.f, 0.f};
        f32x4 Ayv = {0.f, 0.f, 0.f, 0.f};
        f32x4 Azv = {0.f, 0.f, 0.f, 0.f};
        A0v = __builtin_amdgcn_mfma_f32_16x16x32_bf16(aF[0][0], bl0a, A0v, 0, 0, 0);
        A0v = __builtin_amdgcn_mfma_f32_16x16x32_bf16(aF[0][1], bl0b, A0v, 0, 0, 0);
        A0v = __builtin_amdgcn_mfma_f32_16x16x32_bf16(aF[4][0], bl0a, A0v, 0, 0, 0);
        A0v = __builtin_amdgcn_mfma_f32_16x16x32_bf16(aF[4][1], bl0b, A0v, 0, 0, 0);
        Axv = __builtin_amdgcn_mfma_f32_16x16x32_bf16(aF[1][0], bl1a, Axv, 0, 0, 0);
        Axv = __builtin_amdgcn_mfma_f32_16x16x32_bf16(aF[1][1], bl1b, Axv, 0, 0, 0);
        Axv = __builtin_amdgcn_mfma_f32_16x16x32_bf16(aF[5][0], bl1a, Axv, 0, 0, 0);
        Axv = __builtin_amdgcn_mfma_f32_16x16x32_bf16(aF[5][1], bl1b, Axv, 0, 0, 0);
        Ayv = __builtin_amdgcn_mfma_f32_16x16x32_bf16(aF[2][0], bl1a, Ayv, 0, 0, 0);
        Ayv = __builtin_amdgcn_mfma_f32_16x16x32_bf16(aF[2][1], bl1b, Ayv, 0, 0, 0);
        Ayv = __builtin_amdgcn_mfma_f32_16x16x32_bf16(aF[6][0], bl1a, Ayv, 0, 0, 0);
        Ayv = __builtin_amdgcn_mfma_f32_16x16x32_bf16(aF[6][1], bl1b, Ayv, 0, 0, 0);
        Azv = __builtin_amdgcn_mfma_f32_16x16x32_bf16(aF[3][0], bl1a, Azv, 0, 0, 0);
        Azv = __builtin_amdgcn_mfma_f32_16x16x32_bf16(aF[3][1], bl1b, Azv, 0, 0, 0);
        Azv = __builtin_amdgcn_mfma_f32_16x16x32_bf16(aF[7][0], bl1a, Azv, 0, 0, 0);
        Azv = __builtin_amdgcn_mfma_f32_16x16x32_bf16(aF[7][1], bl1b, Azv, 0, 0, 0);

        const float* w0p = &Wsc0[((s << 6) | d) * 5];
        const float c0 = w0p[0], c1 = w0p[1], c2 = w0p[2], c3 = w0p[3], c4 = w0p[4];
        const float4 w1v = *(const float4*)&Wsc1[((s << 6) | d) << 2];

#pragma unroll
        for (int r = 0; r < 4; ++r) {
            const float A0 = A0v[r], Ax = Axv[r], Ay = Ayv[r], Az = Azv[r];
            const float n1 = Ax * Ax + Ay * Ay + Az * Az;
            const float A0sq = A0 * A0;
            const float B0 = c0 * A0 + c1 * A0sq + c2 * A0sq * A0 + c3 * n1 + c4 * A0 * n1;
            const float gg = w1v.x + w1v.y * A0 + w1v.z * A0sq + w1v.w * n1;
            const float bb[4] = {B0, gg * Ax, gg * Ay, gg * Az};
            const int o = swz128(g * 4 + r, 2 * d) >> 1;
#pragma unroll
            for (int p = 0; p < 4; ++p) {
                const unsigned short hi = f2bf1(bb[p]);
                slab[p][o] = hi;
                slab[4 + p][o] = f2bf1(bb[p] - bf2f(hi));
            }
        }
    }
    __syncthreads();

    bf16x8 bF[8][2];
#pragma unroll
    for (int p = 0; p < 8; ++p) {
        bF[p][0] = *(const bf16x8*)&slab[p][swz128(l15, g * 16) >> 1];
        bF[p][1] = *(const bf16x8*)&slab[p][swz128(l15, 64 + g * 16) >> 1];
    }
    const int xnode = nidx[tb + l15];
    bf16x8 xF[4][2];
#pragma unroll
    for (int h = 0; h < 2; ++h) {
#pragma unroll
        for (int j = 0; j < 8; ++j) {
            const int k = h * 32 + g * 8 + j;
            float4 v = make_float4(0.f, 0.f, 0.f, 0.f);
            if (xnode >= 0) v = *(const float4*)&nf[(((size_t)xnode << 6) | k) << 2];
            xF[0][h][j] = (short)f2bf1(v.x);
            xF[1][h][j] = (short)f2bf1(v.y);
            xF[2][h][j] = (short)f2bf1(v.z);
            xF[3][h][j] = (short)f2bf1(v.w);
        }
    }

    const int ndr0 = nidx[tb + g * 4 + 0];
    const int ndr1 = nidx[tb + g * 4 + 1];
    const int ndr2 = nidx[tb + g * 4 + 2];
    const int ndr3 = nidx[tb + g * 4 + 3];

    {
        bf16x8 bp0a = *(const bf16x8*)&WpT0[swz128(d, g * 16) >> 1];
        bf16x8 bp0b = *(const bf16x8*)&WpT0[swz128(d, 64 + g * 16) >> 1];
        bf16x8 bp1a = *(const bf16x8*)&WpT1[swz128(d, g * 16) >> 1];
        bf16x8 bp1b = *(const bf16x8*)&WpT1[swz128(d, 64 + g * 16) >> 1];
        const unsigned short* wr0 = &WrT0[(size_t)s << 12];
        const unsigned short* wr1 = &WrT1[(size_t)s << 12];
        bf16x8 br0a = *(const bf16x8*)&wr0[swz128(d, g * 16) >> 1];
        bf16x8 br0b = *(const bf16x8*)&wr0[swz128(d, 64 + g * 16) >> 1];
        bf16x8 br1a = *(const bf16x8*)&wr1[swz128(d, g * 16) >> 1];
        bf16x8 br1b = *(const bf16x8*)&wr1[swz128(d, 64 + g * 16) >> 1];

        f32x4 F0v = {0.f, 0.f, 0.f, 0.f};
        f32x4 Fxv = {0.f, 0.f, 0.f, 0.f};
        f32x4 Fyv = {0.f, 0.f, 0.f, 0.f};
        f32x4 Fzv = {0.f, 0.f, 0.f, 0.f};
        F0v = __builtin_amdgcn_mfma_f32_16x16x32_bf16(bF[0][0], bp0a, F0v, 0, 0, 0);
        F0v = __builtin_amdgcn_mfma_f32_16x16x32_bf16(bF[0][1], bp0b, F0v, 0, 0, 0);
        F0v = __builtin_amdgcn_mfma_f32_16x16x32_bf16(bF[4][0], bp0a, F0v, 0, 0, 0);
        F0v = __builtin_amdgcn_mfma_f32_16x16x32_bf16(bF[4][1], bp0b, F0v, 0, 0, 0);
        F0v = __builtin_amdgcn_mfma_f32_16x16x32_bf16(xF[0][0], br0a, F0v, 0, 0, 0);
        F0v = __builtin_amdgcn_mfma_f32_16x16x32_bf16(xF[0][1], br0b, F0v, 0, 0, 0);
        Fxv = __builtin_amdgcn_mfma_f32_16x16x32_bf16(bF[1][0], bp1a, Fxv, 0, 0, 0);
        Fxv = __builtin_amdgcn_mfma_f32_16x16x32_bf16(bF[1][1], bp1b, Fxv, 0, 0, 0);
        Fxv = __builtin_amdgcn_mfma_f32_16x16x32_bf16(bF[5][0], bp1a, Fxv, 0, 0, 0);
        Fxv = __builtin_amdgcn_mfma_f32_16x16x32_bf16(bF[5][1], bp1b, Fxv, 0, 0, 0);
        Fxv = __builtin_amdgcn_mfma_f32_16x16x32_bf16(xF[1][0], br1a, Fxv, 0, 0, 0);
        Fxv = __builtin_amdgcn_mfma_f32_16x16x32_bf16(xF[1][1], br1b, Fxv, 0, 0, 0);
        Fyv = __builtin_amdgcn_mfma_f32_16x16x32_bf16(bF[2][0], bp1a, Fyv, 0, 0, 0);
        Fyv = __builtin_amdgcn_mfma_f32_16x16x32_bf16(bF[2][1], bp1b, Fyv, 0, 0, 0);
        Fyv = __builtin_amdgcn_mfma_f32_16x16x32_bf16(bF[6][0], bp1a, Fyv, 0, 0, 0);
        Fyv = __builtin_amdgcn_mfma_f32_16x16x32_bf16(bF[6][1], bp1b, Fyv, 0, 0, 0);
        Fyv = __builtin_amdgcn_mfma_f32_16x16x32_bf16(xF[2][0], br1a, Fyv, 0, 0, 0);
        Fyv = __builtin_amdgcn_mfma_f32_16x16x32_bf16(xF[2][1], br1b, Fyv, 0, 0, 0);
        Fzv = __builtin_amdgcn_mfma_f32_16x16x32_bf16(bF[3][0], bp1a, Fzv, 0, 0, 0);
        Fzv = __builtin_amdgcn_mfma_f32_16x16x32_bf16(bF[3][1], bp1b, Fzv, 0, 0, 0);
        Fzv = __builtin_amdgcn_mfma_f32_16x16x32_bf16(bF[7][0], bp1a, Fzv, 0, 0, 0);
        Fzv = __builtin_amdgcn_mfma_f32_16x16x32_bf16(bF[7][1], bp1b, Fzv, 0, 0, 0);
        Fzv = __builtin_amdgcn_mfma_f32_16x16x32_bf16(xF[3][0], br1a, Fzv, 0, 0, 0);
        Fzv = __builtin_amdgcn_mfma_f32_16x16x32_bf16(xF[3][1], br1b, Fzv, 0, 0, 0);

        const float wdv = Wrd[d];
        if (ndr0 >= 0) *(float4*)&outF[((size_t)ndr0 << 8) + (d << 2)] = make_float4(F0v[0], Fxv[0], Fyv[0], Fzv[0]);
        if (ndr1 >= 0) *(float4*)&outF[((size_t)ndr1 << 8) + (d << 2)] = make_float4(F0v[1], Fxv[1], Fyv[1], Fzv[1]);
        if (ndr2 >= 0) *(float4*)&outF[((size_t)ndr2 << 8) + (d << 2)] = make_float4(F0v[2], Fxv[2], Fyv[2], Fzv[2]);
        if (ndr3 >= 0) *(float4*)&outF[((size_t)ndr3 << 8) + (d << 2)] = make_float4(F0v[3], Fxv[3], Fyv[3], Fzv[3]);

        float ro[4] = {F0v[0] * wdv, F0v[1] * wdv, F0v[2] * wdv, F0v[3] * wdv};
#pragma unroll
        for (int mo = 1; mo < 16; mo <<= 1) {
#pragma unroll
            for (int r = 0; r < 4; ++r) ro[r] += __shfl_xor(ro[r], mo, 64);
        }
        if (l15 == 0) {
#pragma unroll
            for (int r = 0; r < 4; ++r) roS[wvi][g * 4 + r] = ro[r];
        }
    }
    __syncthreads();

    if (tid < 16) {
        const int nd = nidx[tb + tid];
        if (nd >= 0)
            out0[nd] = roS[0][tid] + roS[1][tid] + roS[2][tid] + roS[3][tid];
    }
}

// ===========================================================================
extern "C" void kernel_launch(void* const* d_in, const int* in_sizes, int n_in,
                              void* d_out, int out_size, void* d_ws, size_t ws_size,
                              hipStream_t stream)
{
    const float* edge_vectors = (const float*)d_in[0];
    const float* node_feats   = (const float*)d_in[1];
    const int*   node_species = (const int*)d_in[2];
    const float* radial       = (const float*)d_in[3];
    const int*   senders      = (const int*)d_in[4];
    const int*   receivers    = (const int*)d_in[5];
    const float* W_r1   = (const float*)d_in[6];
    const float* W_r2   = (const float*)d_in[7];
    const float* W_r3   = (const float*)d_in[8];
    const float* W_lin0 = (const float*)d_in[9];
    const float* W_lin1 = (const float*)d_in[10];
    const float* Wsc0   = (const float*)d_in[11];
    const float* Wsc1   = (const float*)d_in[12];
    const float* Wp0    = (const float*)d_in[13];
    const float* Wp1    = (const float*)d_in[14];
    const float* Wres0  = (const float*)d_in[15];
    const float* Wres1  = (const float*)d_in[16];
    const float* W_read = (const float*)d_in[17];

    float* out0 = (float*)d_out;
    float* outF = out0 + kN;

    char* ws = (char*)d_ws;
    unsigned short* m = (unsigned short*)(ws + kOffM);
    int* cnt  = (int*)(ws + kOffCnt);
    int* cnt2 = (int*)(ws + kOffCnt2);
    int* off  = (int*)(ws + kOffOff);
    int* off2 = (int*)(ws + kOffOff2);
    int* cur  = (int*)(ws + kOffCur);
    int* cur2 = (int*)(ws + kOffCur2);
    int* pos  = (int*)(ws + kOffPos);
    int* nidx = (int*)(ws + kOffNidx);
    unsigned short* WlT0 = (unsigned short*)(ws + kOffWlT0);
    unsigned short* WlT1 = (unsigned short*)(ws + kOffWlT1);
    unsigned short* WpT0 = (unsigned short*)(ws + kOffWpT0);
    unsigned short* WpT1 = (unsigned short*)(ws + kOffWpT1);
    unsigned short* WrT0 = (unsigned short*)(ws + kOffWrT0);
    unsigned short* WrT1 = (unsigned short*)(ws + kOffWrT1);

    hipMemsetAsync(cnt, 0, kN * sizeof(int) + 64, stream);
    hipMemsetAsync(nidx, 0xFF, (size_t)kTilesMax * 16 * sizeof(int), stream);

    prep_kernel<<<1024, 256, 0, stream>>>(receivers, node_species,
                                          W_lin0, W_lin1, Wp0, Wp1, Wres0, Wres1,
                                          cnt, cnt2, pos,
                                          WlT0, WlT1, WpT0, WpT1, WrT0, WrT1);
    scan_kernel<<<1, 1024, 0, stream>>>(cnt, off, cur, cnt2, off2, cur2);
    rank_kernel<<<1024, 256, 0, stream>>>(node_species, cur2, nidx);

    edge_mfma<<<256, 512, 0, stream>>>(edge_vectors, node_feats, radial,
                                       senders, receivers, off, pos,
                                       W_r1, W_r2, W_r3, m);

    node_mfma<<<kTilesMax, 256, 0, stream>>>(
        node_feats, node_species,
        WlT0, WlT1, WpT0, WpT1, WrT0, WrT1,
        Wsc0, Wsc1, W_read,
        m, off, nidx, out0, outF);
}

// Round 14
// 411.263 us; speedup vs baseline: 1.0432x; 1.0432x over previous
//
#include <hip/hip_runtime.h>

// MACE layer v14: v12 (passed, 416.5 us; v13's (256,4) regressed -> reverted)
// + ONE change: node_mfma gather unroll 4-deep -> 8-deep leading pass
// (double loads-in-flight; TLP is VGPR-capped so use ILP).
// Everything else byte-identical to v12.

typedef __attribute__((ext_vector_type(8))) short bf16x8;
typedef __attribute__((ext_vector_type(4))) float f32x4;

constexpr int kN = 50000;
constexpr int kE = 400000;
constexpr int kS = 10;
constexpr int kTilesMax = 3150;

// ws layout (bytes)
constexpr size_t kOffM    = 0;           // kE*256 ushort = 204,800,000
constexpr size_t kOffCnt  = 204800000;   // kN int
constexpr size_t kOffCnt2 = 205000000;   // 16 int
constexpr size_t kOffOff  = 205000064;   // kN+1 int
constexpr size_t kOffOff2 = 205200128;   // 16 int
constexpr size_t kOffCur  = 205200192;   // kN int
constexpr size_t kOffCur2 = 205400192;   // 16 int
constexpr size_t kOffPos  = 205400256;   // kE int (local rank within segment)
constexpr size_t kOffNidx = 207000256;   // kTilesMax*16 int
constexpr size_t kOffWlT0 = 207201856;   // 4096 ushort each
constexpr size_t kOffWlT1 = 207210048;
constexpr size_t kOffWpT0 = 207218240;
constexpr size_t kOffWpT1 = 207226432;
constexpr size_t kOffWrT0 = 207234624;   // 10*4096 ushort
constexpr size_t kOffWrT1 = 207316544;   // end 207,398,464

__device__ __forceinline__ float silu_f(float x) {
    float t = __expf(-x);
    return x / (1.0f + t);
}
// manual RNE f32->bf16 (edge path — do NOT replace with cvt_pk asm; r10 NaN)
__device__ __forceinline__ unsigned short f2bf(float f) {
    unsigned u = __float_as_uint(f);
    unsigned r = (u + 0x7FFFu + ((u >> 16) & 1u)) >> 16;
    return (unsigned short)r;
}
// cvt_pk helpers (node path only — proven there)
__device__ __forceinline__ unsigned cvt_pk_bf16(float lo, float hi) {
    unsigned r;
    asm("v_cvt_pk_bf16_f32 %0, %1, %2" : "=v"(r) : "v"(lo), "v"(hi));
    return r;
}
__device__ __forceinline__ unsigned short f2bf1(float x) {
    return (unsigned short)cvt_pk_bf16(x, 0.f);
}
__device__ __forceinline__ float bf2f(unsigned short b) {
    return __uint_as_float(((unsigned)b) << 16);
}
__device__ __forceinline__ int swz128(int row, int byteoff) {
    return row * 128 + (byteoff ^ ((row & 7) << 4));
}

// ---------------------------------------------------------------------------
// prep: edge hist stores local rank -> pos; species hist (LDS-agg); weights
// ---------------------------------------------------------------------------
__global__ __launch_bounds__(256)
void prep_kernel(const int* __restrict__ rcv, const int* __restrict__ spc,
                 const float* __restrict__ Wl0, const float* __restrict__ Wl1,
                 const float* __restrict__ Wp0, const float* __restrict__ Wp1,
                 const float* __restrict__ Wres0, const float* __restrict__ Wres1,
                 int* __restrict__ cnt, int* __restrict__ cnt2,
                 int* __restrict__ pos,
                 unsigned short* __restrict__ WlT0, unsigned short* __restrict__ WlT1,
                 unsigned short* __restrict__ WpT0, unsigned short* __restrict__ WpT1,
                 unsigned short* __restrict__ WrT0, unsigned short* __restrict__ WrT1)
{
    const int tid = threadIdx.x;
    const int gtid = blockIdx.x * 256 + tid;
    const int gstride = gridDim.x * 256;

    for (int i = gtid; i < kE; i += gstride) pos[i] = atomicAdd(&cnt[rcv[i]], 1);

    __shared__ int lh[kS];
    for (int base = blockIdx.x * 256; base < kN; base += gstride) {
        if (tid < kS) lh[tid] = 0;
        __syncthreads();
        int node = base + tid;
        if (node < kN) atomicAdd(&lh[spc[node]], 1);
        __syncthreads();
        if (tid < kS && lh[tid]) atomicAdd(&cnt2[tid], lh[tid]);
        __syncthreads();
    }

    for (int i3 = gtid; i3 < 16384 + 81920; i3 += gstride) {
        if (i3 < 16384) {
            int w = i3 >> 12, r = i3 & 4095, k = r >> 6, n = r & 63;
            const float* src = (w == 0) ? Wl0 : (w == 1) ? Wl1 : (w == 2) ? Wp0 : Wp1;
            unsigned short* dst = (w == 0) ? WlT0 : (w == 1) ? WlT1 : (w == 2) ? WpT0 : WpT1;
            dst[swz128(n, 2 * k) >> 1] = f2bf(src[r]);
        } else {
            int i4 = i3 - 16384;
            int w = i4 / 40960;
            int r5 = i4 - w * 40960;                 // s*4096 + c*64 + d
            int s = r5 >> 12, r = r5 & 4095, k = r >> 6, n = r & 63;
            const float* src = w ? Wres1 : Wres0;
            unsigned short* dst = w ? WrT1 : WrT0;
            dst[(s << 12) + (swz128(n, 2 * k) >> 1)] = f2bf(src[r5]);
        }
    }
}

// ---------------------------------------------------------------------------
__global__ __launch_bounds__(1024)
void scan_kernel(const int* __restrict__ cnt, int* __restrict__ off,
                 int* __restrict__ cur,
                 const int* __restrict__ cnt2, int* __restrict__ off2,
                 int* __restrict__ cur2)
{
    __shared__ int wred[16];
    const int tid = threadIdx.x;
    const int lane = tid & 63;
    const int wv = tid >> 6;
    const int CH = 49;
    const int b = tid * CH;
    int s = 0;
    for (int i = 0; i < CH; ++i) {
        int idx = b + i;
        if (idx < kN) s += cnt[idx];
    }
    int incl = s;
    for (int d = 1; d < 64; d <<= 1) {
        int t = __shfl_up(incl, d, 64);
        if (lane >= d) incl += t;
    }
    if (lane == 63) wred[wv] = incl;
    __syncthreads();
    if (tid < 16) {
        int o = wred[tid];
        int v = o;
        for (int d = 1; d < 16; d <<= 1) {
            int t = __shfl_up(v, d, 64);
            if (tid >= d) v += t;
        }
        wred[tid] = v - o;
    }
    __syncthreads();
    int run = wred[wv] + (incl - s);
    for (int i = 0; i < CH; ++i) {
        int idx = b + i;
        if (idx < kN) {
            int c = cnt[idx];
            off[idx] = run;
            cur[idx] = run;
            run += c;
        }
    }
    if (tid == 0) {
        off[kN] = kE;
        int base = 0;
        for (int sp = 0; sp < kS; ++sp) {
            off2[sp] = base;
            cur2[sp] = base;
            base += (cnt2[sp] + 15) & ~15;
        }
        off2[kS] = base;
    }
}

// ---------------------------------------------------------------------------
__global__ __launch_bounds__(256)
void rank_kernel(const int* __restrict__ spc,
                 int* __restrict__ cur2, int* __restrict__ nidx)
{
    const int tid = threadIdx.x;
    const int gstride = gridDim.x * 256;

    __shared__ int lh[kS];
    __shared__ int gbase[kS];
    for (int base = blockIdx.x * 256; base < kN; base += gstride) {
        if (tid < kS) lh[tid] = 0;
        __syncthreads();
        const int node = base + tid;
        int s = -1, lr = 0;
        if (node < kN) {
            s = spc[node];
            lr = atomicAdd(&lh[s], 1);
        }
        __syncthreads();
        if (tid < kS) gbase[tid] = lh[tid] ? atomicAdd(&cur2[tid], lh[tid]) : 0;
        __syncthreads();
        if (node < kN) nidx[gbase[s] + lr] = node;
        __syncthreads();
    }
}

// ---------------------------------------------------------------------------
// edge_mfma (v12, unchanged). 512 thr (8 waves), 16 edges/wave.
// ---------------------------------------------------------------------------
__global__ __launch_bounds__(512, 1)
void edge_mfma(const float* __restrict__ ev,
               const float* __restrict__ nf,
               const float* __restrict__ rad,
               const int* __restrict__ snd,
               const int* __restrict__ rcv,
               const int* __restrict__ off,
               const int* __restrict__ pos,
               const float* __restrict__ W1,
               const float* __restrict__ W2,
               const float* __restrict__ W3,
               unsigned short* __restrict__ mq)
{
    __shared__ unsigned short W2T[64 * 64];
    __shared__ unsigned short W3T[256 * 64];
    __shared__ unsigned short h1s[8][16 * 64];
    __shared__ unsigned short h2s[8][16 * 64];
    __shared__ unsigned short wTs[8][256 * 20];

    const int tid = threadIdx.x;
    for (int i = tid; i < 64 * 64; i += 512) {
        int k = i >> 6, n = i & 63;
        W2T[swz128(n, 2 * k) >> 1] = f2bf(W2[i]);
    }
    for (int i = tid; i < 256 * 64; i += 512) {
        int k = i >> 8, n = i & 255;
        W3T[swz128(n, 2 * k) >> 1] = f2bf(W3[i]);
    }
    __syncthreads();

    const int lane = tid & 63;
    const int wvi = tid >> 6;
    const int l15 = lane & 15;
    const int g = lane >> 4;

    float w1r[8];
#pragma unroll
    for (int r = 0; r < 8; ++r) w1r[r] = W1[(r << 6) | lane];

    unsigned short* h1w = h1s[wvi];
    unsigned short* h2w = h2s[wvi];
    unsigned short* wTw = wTs[wvi];

    for (int t = blockIdx.x; t < kE / 128; t += gridDim.x) {
        const int et = t * 128 + wvi * 16;

        for (int e = 0; e < 16; ++e) {
            const float4 ra = *(const float4*)&rad[(size_t)(et + e) * 8];
            const float4 rb = *(const float4*)&rad[(size_t)(et + e) * 8 + 4];
            float acc = ra.x * w1r[0] + ra.y * w1r[1] + ra.z * w1r[2] + ra.w * w1r[3]
                      + rb.x * w1r[4] + rb.y * w1r[5] + rb.z * w1r[6] + rb.w * w1r[7];
            h1w[swz128(e, 2 * lane) >> 1] = f2bf(silu_f(acc));
        }
        __builtin_amdgcn_wave_barrier();

        bf16x8 a0 = *(const bf16x8*)&h1w[swz128(l15, g * 16) >> 1];
        bf16x8 a1 = *(const bf16x8*)&h1w[swz128(l15, 64 + g * 16) >> 1];

#pragma unroll
        for (int n0 = 0; n0 < 64; n0 += 16) {
            const int n = n0 + l15;
            bf16x8 b0 = *(const bf16x8*)&W2T[swz128(n, g * 16) >> 1];
            bf16x8 b1 = *(const bf16x8*)&W2T[swz128(n, 64 + g * 16) >> 1];
            f32x4 acc = {0.f, 0.f, 0.f, 0.f};
            acc = __builtin_amdgcn_mfma_f32_16x16x32_bf16(a0, b0, acc, 0, 0, 0);
            acc = __builtin_amdgcn_mfma_f32_16x16x32_bf16(a1, b1, acc, 0, 0, 0);
#pragma unroll
            for (int r = 0; r < 4; ++r) {
                int e2 = g * 4 + r;
                h2w[swz128(e2, 2 * n) >> 1] = f2bf(silu_f(acc[r]));
            }
        }
        __builtin_amdgcn_wave_barrier();

        bf16x8 c0 = *(const bf16x8*)&h2w[swz128(l15, g * 16) >> 1];
        bf16x8 c1 = *(const bf16x8*)&h2w[swz128(l15, 64 + g * 16) >> 1];
#pragma unroll
        for (int m0 = 0; m0 < 16; ++m0) {
            const int nrow = m0 * 16 + l15;
            bf16x8 wa0 = *(const bf16x8*)&W3T[swz128(nrow, g * 16) >> 1];
            bf16x8 wa1 = *(const bf16x8*)&W3T[swz128(nrow, 64 + g * 16) >> 1];
            f32x4 acc = {0.f, 0.f, 0.f, 0.f};
            acc = __builtin_amdgcn_mfma_f32_16x16x32_bf16(wa0, c0, acc, 0, 0, 0);
            acc = __builtin_amdgcn_mfma_f32_16x16x32_bf16(wa1, c1, acc, 0, 0, 0);
#pragma unroll
            for (int r = 0; r < 4; ++r) {
                int nn = m0 * 16 + g * 4 + r;
                wTw[nn * 20 + l15] = f2bf(acc[r]);
            }
        }
        __builtin_amdgcn_wave_barrier();

        const int c = lane;
#pragma unroll
        for (int grp = 0; grp < 4; ++grp) {
            ushort4 qa[4];
#pragma unroll
            for (int k = 0; k < 4; ++k)
                qa[k] = *(const ushort4*)&wTw[(k * 64 + c) * 20 + grp * 4];
            const unsigned short* qp = (const unsigned short*)qa;
#pragma unroll
            for (int e = 0; e < 4; ++e) {
                const int eid = et + grp * 4 + e;
                const int sid = snd[eid];
                const int p = off[rcv[eid]] + pos[eid];
                const float ex = ev[(size_t)eid * 3 + 0];
                const float ey = ev[(size_t)eid * 3 + 1];
                const float ez = ev[(size_t)eid * 3 + 2];
                const float ri = rsqrtf(ex * ex + ey * ey + ez * ez + 1e-12f);
                const float y0 = 1.7320508075688772f * ex * ri;
                const float y1 = 1.7320508075688772f * ey * ri;
                const float y2 = 1.7320508075688772f * ez * ri;
                const float4 xv = *(const float4*)&nf[(((size_t)sid << 6) | c) << 2];
                const float w0 = bf2f(qp[0 * 4 + e]);
                const float w1 = bf2f(qp[1 * 4 + e]);
                const float w2v = bf2f(qp[2 * 4 + e]);
                const float w3v = bf2f(qp[3 * 4 + e]);
                const float dot1 = xv.y * y0 + xv.z * y1 + xv.w * y2;
                const float m0v = w0 * xv.x + w1 * dot1;
                const float t2 = w2v * xv.x;
                ushort4 q;
                q.x = f2bf(m0v);
                q.y = f2bf(t2 * y0 + w3v * xv.y);
                q.z = f2bf(t2 * y1 + w3v * xv.z);
                q.w = f2bf(t2 * y2 + w3v * xv.w);
                *(ushort4*)&mq[((size_t)p << 8) + (c << 2)] = q;
            }
        }
        __builtin_amdgcn_wave_barrier();
    }
}

// ---------------------------------------------------------------------------
// node_mfma (v12 + 8-deep gather): block (4 waves) per 16-node tile;
// hi/lo slab.
// ---------------------------------------------------------------------------
__global__ __launch_bounds__(256, 2)
void node_mfma(const float* __restrict__ nf, const int* __restrict__ spc,
               const unsigned short* __restrict__ WlT0, const unsigned short* __restrict__ WlT1,
               const unsigned short* __restrict__ WpT0, const unsigned short* __restrict__ WpT1,
               const unsigned short* __restrict__ WrT0, const unsigned short* __restrict__ WrT1,
               const float* __restrict__ Wsc0, const float* __restrict__ Wsc1,
               const float* __restrict__ Wrd,
               const unsigned short* __restrict__ m, const int* __restrict__ off,
               const int* __restrict__ nidx,
               float* __restrict__ out0, float* __restrict__ outF)
{
    __shared__ unsigned short slab[8][1024];   // planes 0-3 hi, 4-7 lo (16 KB)
    __shared__ float roS[4][16];

    const int tid = threadIdx.x;
    const int lane = tid & 63;
    const int wvi = tid >> 6;
    const int l15 = lane & 15;
    const int g = lane >> 4;
    const int tb = (int)blockIdx.x << 4;

    const int c = lane;
    for (int e4 = 0; e4 < 4; ++e4) {
        const int e = wvi * 4 + e4;
        const int node = nidx[tb + e];
        float ax = 0.f, ay = 0.f, az = 0.f, aw = 0.f;
        if (node >= 0) {
            const int beg = off[node], end = off[node + 1];
            int i = beg;
            for (; i + 8 <= end; i += 8) {
                const ushort4 q0 = *(const ushort4*)&m[((size_t)(i + 0) << 8) + (c << 2)];
                const ushort4 q1 = *(const ushort4*)&m[((size_t)(i + 1) << 8) + (c << 2)];
                const ushort4 q2 = *(const ushort4*)&m[((size_t)(i + 2) << 8) + (c << 2)];
                const ushort4 q3 = *(const ushort4*)&m[((size_t)(i + 3) << 8) + (c << 2)];
                const ushort4 q4 = *(const ushort4*)&m[((size_t)(i + 4) << 8) + (c << 2)];
                const ushort4 q5 = *(const ushort4*)&m[((size_t)(i + 5) << 8) + (c << 2)];
                const ushort4 q6 = *(const ushort4*)&m[((size_t)(i + 6) << 8) + (c << 2)];
                const ushort4 q7 = *(const ushort4*)&m[((size_t)(i + 7) << 8) + (c << 2)];
                ax += ((bf2f(q0.x) + bf2f(q1.x)) + (bf2f(q2.x) + bf2f(q3.x)))
                    + ((bf2f(q4.x) + bf2f(q5.x)) + (bf2f(q6.x) + bf2f(q7.x)));
                ay += ((bf2f(q0.y) + bf2f(q1.y)) + (bf2f(q2.y) + bf2f(q3.y)))
                    + ((bf2f(q4.y) + bf2f(q5.y)) + (bf2f(q6.y) + bf2f(q7.y)));
                az += ((bf2f(q0.z) + bf2f(q1.z)) + (bf2f(q2.z) + bf2f(q3.z)))
                    + ((bf2f(q4.z) + bf2f(q5.z)) + (bf2f(q6.z) + bf2f(q7.z)));
                aw += ((bf2f(q0.w) + bf2f(q1.w)) + (bf2f(q2.w) + bf2f(q3.w)))
                    + ((bf2f(q4.w) + bf2f(q5.w)) + (bf2f(q6.w) + bf2f(q7.w)));
            }
            for (; i + 4 <= end; i += 4) {
                const ushort4 q0 = *(const ushort4*)&m[((size_t)(i + 0) << 8) + (c << 2)];
                const ushort4 q1 = *(const ushort4*)&m[((size_t)(i + 1) << 8) + (c << 2)];
                const ushort4 q2 = *(const ushort4*)&m[((size_t)(i + 2) << 8) + (c << 2)];
                const ushort4 q3 = *(const ushort4*)&m[((size_t)(i + 3) << 8) + (c << 2)];
                ax += (bf2f(q0.x) + bf2f(q1.x)) + (bf2f(q2.x) + bf2f(q3.x));
                ay += (bf2f(q0.y) + bf2f(q1.y)) + (bf2f(q2.y) + bf2f(q3.y));
                az += (bf2f(q0.z) + bf2f(q1.z)) + (bf2f(q2.z) + bf2f(q3.z));
                aw += (bf2f(q0.w) + bf2f(q1.w)) + (bf2f(q2.w) + bf2f(q3.w));
            }
            for (; i < end; ++i) {
                const ushort4 q = *(const ushort4*)&m[((size_t)i << 8) + (c << 2)];
                ax += bf2f(q.x); ay += bf2f(q.y); az += bf2f(q.z); aw += bf2f(q.w);
            }
        }
        const float vv[4] = {ax * 0.125f, ay * 0.125f, az * 0.125f, aw * 0.125f};
        const int o = swz128(e, 2 * c) >> 1;
#pragma unroll
        for (int p = 0; p < 4; ++p) {
            const unsigned short hi = f2bf1(vv[p]);
            slab[p][o] = hi;
            slab[4 + p][o] = f2bf1(vv[p] - bf2f(hi));
        }
    }
    __syncthreads();

    const int n0 = nidx[tb];
    if (n0 < 0) return;
    const int s = spc[n0];

    bf16x8 aF[8][2];
#pragma unroll
    for (int p = 0; p < 8; ++p) {
        aF[p][0] = *(const bf16x8*)&slab[p][swz128(l15, g * 16) >> 1];
        aF[p][1] = *(const bf16x8*)&slab[p][swz128(l15, 64 + g * 16) >> 1];
    }
    __syncthreads();

    const int d = l15 + 16 * wvi;
    {
        bf16x8 bl0a = *(const bf16x8*)&WlT0[swz128(d, g * 16) >> 1];
        bf16x8 bl0b = *(const bf16x8*)&WlT0[swz128(d, 64 + g * 16) >> 1];
        bf16x8 bl1a = *(const bf16x8*)&WlT1[swz128(d, g * 16) >> 1];
        bf16x8 bl1b = *(const bf16x8*)&WlT1[swz128(d, 64 + g * 16) >> 1];
        f32x4 A0v = {0.f, 0.f, 0.f, 0.f};
        f32x4 Axv = {0.f, 0.f, 0.f, 0.f};
        f32x4 Ayv = {0.f, 0.f, 0.f, 0.f};
        f32x4 Azv = {0.f, 0.f, 0.f, 0.f};
        A0v = __builtin_amdgcn_mfma_f32_16x16x32_bf16(aF[0][0], bl0a, A0v, 0, 0, 0);
        A0v = __builtin_amdgcn_mfma_f32_16x16x32_bf16(aF[0][1], bl0b, A0v, 0, 0, 0);
        A0v = __builtin_amdgcn_mfma_f32_16x16x32_bf16(aF[4][0], bl0a, A0v, 0, 0, 0);
        A0v = __builtin_amdgcn_mfma_f32_16x16x32_bf16(aF[4][1], bl0b, A0v, 0, 0, 0);
        Axv = __builtin_amdgcn_mfma_f32_16x16x32_bf16(aF[1][0], bl1a, Axv, 0, 0, 0);
        Axv = __builtin_amdgcn_mfma_f32_16x16x32_bf16(aF[1][1], bl1b, Axv, 0, 0, 0);
        Axv = __builtin_amdgcn_mfma_f32_16x16x32_bf16(aF[5][0], bl1a, Axv, 0, 0, 0);
        Axv = __builtin_amdgcn_mfma_f32_16x16x32_bf16(aF[5][1], bl1b, Axv, 0, 0, 0);
        Ayv = __builtin_amdgcn_mfma_f32_16x16x32_bf16(aF[2][0], bl1a, Ayv, 0, 0, 0);
        Ayv = __builtin_amdgcn_mfma_f32_16x16x32_bf16(aF[2][1], bl1b, Ayv, 0, 0, 0);
        Ayv = __builtin_amdgcn_mfma_f32_16x16x32_bf16(aF[6][0], bl1a, Ayv, 0, 0, 0);
        Ayv = __builtin_amdgcn_mfma_f32_16x16x32_bf16(aF[6][1], bl1b, Ayv, 0, 0, 0);
        Azv = __builtin_amdgcn_mfma_f32_16x16x32_bf16(aF[3][0], bl1a, Azv, 0, 0, 0);
        Azv = __builtin_amdgcn_mfma_f32_16x16x32_bf16(aF[3][1], bl1b, Azv, 0, 0, 0);
        Azv = __builtin_amdgcn_mfma_f32_16x16x32_bf16(aF[7][0], bl1a, Azv, 0, 0, 0);
        Azv = __builtin_amdgcn_mfma_f32_16x16x32_bf16(aF[7][1], bl1b, Azv, 0, 0, 0);

        const float* w0p = &Wsc0[((s << 6) | d) * 5];
        const float c0 = w0p[0], c1 = w0p[1], c2 = w0p[2], c3 = w0p[3], c4 = w0p[4];
        const float4 w1v = *(const float4*)&Wsc1[((s << 6) | d) << 2];

#pragma unroll
        for (int r = 0; r < 4; ++r) {
            const float A0 = A0v[r], Ax = Axv[r], Ay = Ayv[r], Az = Azv[r];
            const float n1 = Ax * Ax + Ay * Ay + Az * Az;
            const float A0sq = A0 * A0;
            const float B0 = c0 * A0 + c1 * A0sq + c2 * A0sq * A0 + c3 * n1 + c4 * A0 * n1;
            const float gg = w1v.x + w1v.y * A0 + w1v.z * A0sq + w1v.w * n1;
            const float bb[4] = {B0, gg * Ax, gg * Ay, gg * Az};
            const int o = swz128(g * 4 + r, 2 * d) >> 1;
#pragma unroll
            for (int p = 0; p < 4; ++p) {
                const unsigned short hi = f2bf1(bb[p]);
                slab[p][o] = hi;
                slab[4 + p][o] = f2bf1(bb[p] - bf2f(hi));
            }
        }
    }
    __syncthreads();

    bf16x8 bF[8][2];
#pragma unroll
    for (int p = 0; p < 8; ++p) {
        bF[p][0] = *(const bf16x8*)&slab[p][swz128(l15, g * 16) >> 1];
        bF[p][1] = *(const bf16x8*)&slab[p][swz128(l15, 64 + g * 16) >> 1];
    }
    const int xnode = nidx[tb + l15];
    bf16x8 xF[4][2];
#pragma unroll
    for (int h = 0; h < 2; ++h) {
#pragma unroll
        for (int j = 0; j < 8; ++j) {
            const int k = h * 32 + g * 8 + j;
            float4 v = make_float4(0.f, 0.f, 0.f, 0.f);
            if (xnode >= 0) v = *(const float4*)&nf[(((size_t)xnode << 6) | k) << 2];
            xF[0][h][j] = (short)f2bf1(v.x);
            xF[1][h][j] = (short)f2bf1(v.y);
            xF[2][h][j] = (short)f2bf1(v.z);
            xF[3][h][j] = (short)f2bf1(v.w);
        }
    }

    const int ndr0 = nidx[tb + g * 4 + 0];
    const int ndr1 = nidx[tb + g * 4 + 1];
    const int ndr2 = nidx[tb + g * 4 + 2];
    const int ndr3 = nidx[tb + g * 4 + 3];

    {
        bf16x8 bp0a = *(const bf16x8*)&WpT0[swz128(d, g * 16) >> 1];
        bf16x8 bp0b = *(const bf16x8*)&WpT0[swz128(d, 64 + g * 16) >> 1];
        bf16x8 bp1a = *(const bf16x8*)&WpT1[swz128(d, g * 16) >> 1];
        bf16x8 bp1b = *(const bf16x8*)&WpT1[swz128(d, 64 + g * 16) >> 1];
        const unsigned short* wr0 = &WrT0[(size_t)s << 12];
        const unsigned short* wr1 = &WrT1[(size_t)s << 12];
        bf16x8 br0a = *(const bf16x8*)&wr0[swz128(d, g * 16) >> 1];
        bf16x8 br0b = *(const bf16x8*)&wr0[swz128(d, 64 + g * 16) >> 1];
        bf16x8 br1a = *(const bf16x8*)&wr1[swz128(d, g * 16) >> 1];
        bf16x8 br1b = *(const bf16x8*)&wr1[swz128(d, 64 + g * 16) >> 1];

        f32x4 F0v = {0.f, 0.f, 0.f, 0.f};
        f32x4 Fxv = {0.f, 0.f, 0.f, 0.f};
        f32x4 Fyv = {0.f, 0.f, 0.f, 0.f};
        f32x4 Fzv = {0.f, 0.f, 0.f, 0.f};
        F0v = __builtin_amdgcn_mfma_f32_16x16x32_bf16(bF[0][0], bp0a, F0v, 0, 0, 0);
        F0v = __builtin_amdgcn_mfma_f32_16x16x32_bf16(bF[0][1], bp0b, F0v, 0, 0, 0);
        F0v = __builtin_amdgcn_mfma_f32_16x16x32_bf16(bF[4][0], bp0a, F0v, 0, 0, 0);
        F0v = __builtin_amdgcn_mfma_f32_16x16x32_bf16(bF[4][1], bp0b, F0v, 0, 0, 0);
        F0v = __builtin_amdgcn_mfma_f32_16x16x32_bf16(xF[0][0], br0a, F0v, 0, 0, 0);
        F0v = __builtin_amdgcn_mfma_f32_16x16x32_bf16(xF[0][1], br0b, F0v, 0, 0, 0);
        Fxv = __builtin_amdgcn_mfma_f32_16x16x32_bf16(bF[1][0], bp1a, Fxv, 0, 0, 0);
        Fxv = __builtin_amdgcn_mfma_f32_16x16x32_bf16(bF[1][1], bp1b, Fxv, 0, 0, 0);
        Fxv = __builtin_amdgcn_mfma_f32_16x16x32_bf16(bF[5][0], bp1a, Fxv, 0, 0, 0);
        Fxv = __builtin_amdgcn_mfma_f32_16x16x32_bf16(bF[5][1], bp1b, Fxv, 0, 0, 0);
        Fxv = __builtin_amdgcn_mfma_f32_16x16x32_bf16(xF[1][0], br1a, Fxv, 0, 0, 0);
        Fxv = __builtin_amdgcn_mfma_f32_16x16x32_bf16(xF[1][1], br1b, Fxv, 0, 0, 0);
        Fyv = __builtin_amdgcn_mfma_f32_16x16x32_bf16(bF[2][0], bp1a, Fyv, 0, 0, 0);
        Fyv = __builtin_amdgcn_mfma_f32_16x16x32_bf16(bF[2][1], bp1b, Fyv, 0, 0, 0);
        Fyv = __builtin_amdgcn_mfma_f32_16x16x32_bf16(bF[6][0], bp1a, Fyv, 0, 0, 0);
        Fyv = __builtin_amdgcn_mfma_f32_16x16x32_bf16(bF[6][1], bp1b, Fyv, 0, 0, 0);
        Fyv = __builtin_amdgcn_mfma_f32_16x16x32_bf16(xF[2][0], br1a, Fyv, 0, 0, 0);
        Fyv = __builtin_amdgcn_mfma_f32_16x16x32_bf16(xF[2][1], br1b, Fyv, 0, 0, 0);
        Fzv = __builtin_amdgcn_mfma_f32_16x16x32_bf16(bF[3][0], bp1a, Fzv, 0, 0, 0);
        Fzv = __builtin_amdgcn_mfma_f32_16x16x32_bf16(bF[3][1], bp1b, Fzv, 0, 0, 0);
        Fzv = __builtin_amdgcn_mfma_f32_16x16x32_bf16(bF[7][0], bp1a, Fzv, 0, 0, 0);
        Fzv = __builtin_amdgcn_mfma_f32_16x16x32_bf16(bF[7][1], bp1b, Fzv, 0, 0, 0);
        Fzv = __builtin_amdgcn_mfma_f32_16x16x32_bf16(xF[3][0], br1a, Fzv, 0, 0, 0);
        Fzv = __builtin_amdgcn_mfma_f32_16x16x32_bf16(xF[3][1], br1b, Fzv, 0, 0, 0);

        const float wdv = Wrd[d];
        if (ndr0 >= 0) *(float4*)&outF[((size_t)ndr0 << 8) + (d << 2)] = make_float4(F0v[0], Fxv[0], Fyv[0], Fzv[0]);
        if (ndr1 >= 0) *(float4*)&outF[((size_t)ndr1 << 8) + (d << 2)] = make_float4(F0v[1], Fxv[1], Fyv[1], Fzv[1]);
        if (ndr2 >= 0) *(float4*)&outF[((size_t)ndr2 << 8) + (d << 2)] = make_float4(F0v[2], Fxv[2], Fyv[2], Fzv[2]);
        if (ndr3 >= 0) *(float4*)&outF[((size_t)ndr3 << 8) + (d << 2)] = make_float4(F0v[3], Fxv[3], Fyv[3], Fzv[3]);

        float ro[4] = {F0v[0] * wdv, F0v[1] * wdv, F0v[2] * wdv, F0v[3] * wdv};
#pragma unroll
        for (int mo = 1; mo < 16; mo <<= 1) {
#pragma unroll
            for (int r = 0; r < 4; ++r) ro[r] += __shfl_xor(ro[r], mo, 64);
        }
        if (l15 == 0) {
#pragma unroll
            for (int r = 0; r < 4; ++r) roS[wvi][g * 4 + r] = ro[r];
        }
    }
    __syncthreads();

    if (tid < 16) {
        const int nd = nidx[tb + tid];
        if (nd >= 0)
            out0[nd] = roS[0][tid] + roS[1][tid] + roS[2][tid] + roS[3][tid];
    }
}

// ===========================================================================
extern "C" void kernel_launch(void* const* d_in, const int* in_sizes, int n_in,
                              void* d_out, int out_size, void* d_ws, size_t ws_size,
                              hipStream_t stream)
{
    const float* edge_vectors = (const float*)d_in[0];
    const float* node_feats   = (const float*)d_in[1];
    const int*   node_species = (const int*)d_in[2];
    const float* radial       = (const float*)d_in[3];
    const int*   senders      = (const int*)d_in[4];
    const int*   receivers    = (const int*)d_in[5];
    const float* W_r1   = (const float*)d_in[6];
    const float* W_r2   = (const float*)d_in[7];
    const float* W_r3   = (const float*)d_in[8];
    const float* W_lin0 = (const float*)d_in[9];
    const float* W_lin1 = (const float*)d_in[10];
    const float* Wsc0   = (const float*)d_in[11];
    const float* Wsc1   = (const float*)d_in[12];
    const float* Wp0    = (const float*)d_in[13];
    const float* Wp1    = (const float*)d_in[14];
    const float* Wres0  = (const float*)d_in[15];
    const float* Wres1  = (const float*)d_in[16];
    const float* W_read = (const float*)d_in[17];

    float* out0 = (float*)d_out;
    float* outF = out0 + kN;

    char* ws = (char*)d_ws;
    unsigned short* m = (unsigned short*)(ws + kOffM);
    int* cnt  = (int*)(ws + kOffCnt);
    int* cnt2 = (int*)(ws + kOffCnt2);
    int* off  = (int*)(ws + kOffOff);
    int* off2 = (int*)(ws + kOffOff2);
    int* cur  = (int*)(ws + kOffCur);
    int* cur2 = (int*)(ws + kOffCur2);
    int* pos  = (int*)(ws + kOffPos);
    int* nidx = (int*)(ws + kOffNidx);
    unsigned short* WlT0 = (unsigned short*)(ws + kOffWlT0);
    unsigned short* WlT1 = (unsigned short*)(ws + kOffWlT1);
    unsigned short* WpT0 = (unsigned short*)(ws + kOffWpT0);
    unsigned short* WpT1 = (unsigned short*)(ws + kOffWpT1);
    unsigned short* WrT0 = (unsigned short*)(ws + kOffWrT0);
    unsigned short* WrT1 = (unsigned short*)(ws + kOffWrT1);

    hipMemsetAsync(cnt, 0, kN * sizeof(int) + 64, stream);
    hipMemsetAsync(nidx, 0xFF, (size_t)kTilesMax * 16 * sizeof(int), stream);

    prep_kernel<<<1024, 256, 0, stream>>>(receivers, node_species,
                                          W_lin0, W_lin1, Wp0, Wp1, Wres0, Wres1,
                                          cnt, cnt2, pos,
                                          WlT0, WlT1, WpT0, WpT1, WrT0, WrT1);
    scan_kernel<<<1, 1024, 0, stream>>>(cnt, off, cur, cnt2, off2, cur2);
    rank_kernel<<<1024, 256, 0, stream>>>(node_species, cur2, nidx);

    edge_mfma<<<256, 512, 0, stream>>>(edge_vectors, node_feats, radial,
                                       senders, receivers, off, pos,
                                       W_r1, W_r2, W_r3, m);

    node_mfma<<<kTilesMax, 256, 0, stream>>>(
        node_feats, node_species,
        WlT0, WlT1, WpT0, WpT1, WrT0, WrT1,
        Wsc0, Wsc1, W_read,
        m, off, nidx, out0, outF);
}

// Round 15
// 393.584 us; speedup vs baseline: 1.0900x; 1.0449x over previous
//
#include <hip/hip_runtime.h>

// MACE layer v15: v14 (passed, 411.3 us) + ONE change: edge_mfma Phase D
// edge scalars (sid, p, y0..y2) hoisted to per-lane precompute (lane l15 owns
// edge et+l15) + __shfl broadcast in the D loop. Loads overlap phases A-C.
// Everything else byte-identical to v14.

typedef __attribute__((ext_vector_type(8))) short bf16x8;
typedef __attribute__((ext_vector_type(4))) float f32x4;

constexpr int kN = 50000;
constexpr int kE = 400000;
constexpr int kS = 10;
constexpr int kTilesMax = 3150;

// ws layout (bytes)
constexpr size_t kOffM    = 0;           // kE*256 ushort = 204,800,000
constexpr size_t kOffCnt  = 204800000;   // kN int
constexpr size_t kOffCnt2 = 205000000;   // 16 int
constexpr size_t kOffOff  = 205000064;   // kN+1 int
constexpr size_t kOffOff2 = 205200128;   // 16 int
constexpr size_t kOffCur  = 205200192;   // kN int
constexpr size_t kOffCur2 = 205400192;   // 16 int
constexpr size_t kOffPos  = 205400256;   // kE int (local rank within segment)
constexpr size_t kOffNidx = 207000256;   // kTilesMax*16 int
constexpr size_t kOffWlT0 = 207201856;   // 4096 ushort each
constexpr size_t kOffWlT1 = 207210048;
constexpr size_t kOffWpT0 = 207218240;
constexpr size_t kOffWpT1 = 207226432;
constexpr size_t kOffWrT0 = 207234624;   // 10*4096 ushort
constexpr size_t kOffWrT1 = 207316544;   // end 207,398,464

__device__ __forceinline__ float silu_f(float x) {
    float t = __expf(-x);
    return x / (1.0f + t);
}
// manual RNE f32->bf16 (edge path — do NOT replace with cvt_pk asm; r10 NaN)
__device__ __forceinline__ unsigned short f2bf(float f) {
    unsigned u = __float_as_uint(f);
    unsigned r = (u + 0x7FFFu + ((u >> 16) & 1u)) >> 16;
    return (unsigned short)r;
}
// cvt_pk helpers (node path only — proven there)
__device__ __forceinline__ unsigned cvt_pk_bf16(float lo, float hi) {
    unsigned r;
    asm("v_cvt_pk_bf16_f32 %0, %1, %2" : "=v"(r) : "v"(lo), "v"(hi));
    return r;
}
__device__ __forceinline__ unsigned short f2bf1(float x) {
    return (unsigned short)cvt_pk_bf16(x, 0.f);
}
__device__ __forceinline__ float bf2f(unsigned short b) {
    return __uint_as_float(((unsigned)b) << 16);
}
__device__ __forceinline__ int swz128(int row, int byteoff) {
    return row * 128 + (byteoff ^ ((row & 7) << 4));
}

// ---------------------------------------------------------------------------
// prep: edge hist stores local rank -> pos; species hist (LDS-agg); weights
// ---------------------------------------------------------------------------
__global__ __launch_bounds__(256)
void prep_kernel(const int* __restrict__ rcv, const int* __restrict__ spc,
                 const float* __restrict__ Wl0, const float* __restrict__ Wl1,
                 const float* __restrict__ Wp0, const float* __restrict__ Wp1,
                 const float* __restrict__ Wres0, const float* __restrict__ Wres1,
                 int* __restrict__ cnt, int* __restrict__ cnt2,
                 int* __restrict__ pos,
                 unsigned short* __restrict__ WlT0, unsigned short* __restrict__ WlT1,
                 unsigned short* __restrict__ WpT0, unsigned short* __restrict__ WpT1,
                 unsigned short* __restrict__ WrT0, unsigned short* __restrict__ WrT1)
{
    const int tid = threadIdx.x;
    const int gtid = blockIdx.x * 256 + tid;
    const int gstride = gridDim.x * 256;

    for (int i = gtid; i < kE; i += gstride) pos[i] = atomicAdd(&cnt[rcv[i]], 1);

    __shared__ int lh[kS];
    for (int base = blockIdx.x * 256; base < kN; base += gstride) {
        if (tid < kS) lh[tid] = 0;
        __syncthreads();
        int node = base + tid;
        if (node < kN) atomicAdd(&lh[spc[node]], 1);
        __syncthreads();
        if (tid < kS && lh[tid]) atomicAdd(&cnt2[tid], lh[tid]);
        __syncthreads();
    }

    for (int i3 = gtid; i3 < 16384 + 81920; i3 += gstride) {
        if (i3 < 16384) {
            int w = i3 >> 12, r = i3 & 4095, k = r >> 6, n = r & 63;
            const float* src = (w == 0) ? Wl0 : (w == 1) ? Wl1 : (w == 2) ? Wp0 : Wp1;
            unsigned short* dst = (w == 0) ? WlT0 : (w == 1) ? WlT1 : (w == 2) ? WpT0 : WpT1;
            dst[swz128(n, 2 * k) >> 1] = f2bf(src[r]);
        } else {
            int i4 = i3 - 16384;
            int w = i4 / 40960;
            int r5 = i4 - w * 40960;                 // s*4096 + c*64 + d
            int s = r5 >> 12, r = r5 & 4095, k = r >> 6, n = r & 63;
            const float* src = w ? Wres1 : Wres0;
            unsigned short* dst = w ? WrT1 : WrT0;
            dst[(s << 12) + (swz128(n, 2 * k) >> 1)] = f2bf(src[r5]);
        }
    }
}

// ---------------------------------------------------------------------------
__global__ __launch_bounds__(1024)
void scan_kernel(const int* __restrict__ cnt, int* __restrict__ off,
                 int* __restrict__ cur,
                 const int* __restrict__ cnt2, int* __restrict__ off2,
                 int* __restrict__ cur2)
{
    __shared__ int wred[16];
    const int tid = threadIdx.x;
    const int lane = tid & 63;
    const int wv = tid >> 6;
    const int CH = 49;
    const int b = tid * CH;
    int s = 0;
    for (int i = 0; i < CH; ++i) {
        int idx = b + i;
        if (idx < kN) s += cnt[idx];
    }
    int incl = s;
    for (int d = 1; d < 64; d <<= 1) {
        int t = __shfl_up(incl, d, 64);
        if (lane >= d) incl += t;
    }
    if (lane == 63) wred[wv] = incl;
    __syncthreads();
    if (tid < 16) {
        int o = wred[tid];
        int v = o;
        for (int d = 1; d < 16; d <<= 1) {
            int t = __shfl_up(v, d, 64);
            if (tid >= d) v += t;
        }
        wred[tid] = v - o;
    }
    __syncthreads();
    int run = wred[wv] + (incl - s);
    for (int i = 0; i < CH; ++i) {
        int idx = b + i;
        if (idx < kN) {
            int c = cnt[idx];
            off[idx] = run;
            cur[idx] = run;
            run += c;
        }
    }
    if (tid == 0) {
        off[kN] = kE;
        int base = 0;
        for (int sp = 0; sp < kS; ++sp) {
            off2[sp] = base;
            cur2[sp] = base;
            base += (cnt2[sp] + 15) & ~15;
        }
        off2[kS] = base;
    }
}

// ---------------------------------------------------------------------------
__global__ __launch_bounds__(256)
void rank_kernel(const int* __restrict__ spc,
                 int* __restrict__ cur2, int* __restrict__ nidx)
{
    const int tid = threadIdx.x;
    const int gstride = gridDim.x * 256;

    __shared__ int lh[kS];
    __shared__ int gbase[kS];
    for (int base = blockIdx.x * 256; base < kN; base += gstride) {
        if (tid < kS) lh[tid] = 0;
        __syncthreads();
        const int node = base + tid;
        int s = -1, lr = 0;
        if (node < kN) {
            s = spc[node];
            lr = atomicAdd(&lh[s], 1);
        }
        __syncthreads();
        if (tid < kS) gbase[tid] = lh[tid] ? atomicAdd(&cur2[tid], lh[tid]) : 0;
        __syncthreads();
        if (node < kN) nidx[gbase[s] + lr] = node;
        __syncthreads();
    }
}

// ---------------------------------------------------------------------------
// edge_mfma (v14 + Phase D scalar hoist/shfl). 512 thr (8 waves), 16 edges/wave.
// ---------------------------------------------------------------------------
__global__ __launch_bounds__(512, 1)
void edge_mfma(const float* __restrict__ ev,
               const float* __restrict__ nf,
               const float* __restrict__ rad,
               const int* __restrict__ snd,
               const int* __restrict__ rcv,
               const int* __restrict__ off,
               const int* __restrict__ pos,
               const float* __restrict__ W1,
               const float* __restrict__ W2,
               const float* __restrict__ W3,
               unsigned short* __restrict__ mq)
{
    __shared__ unsigned short W2T[64 * 64];
    __shared__ unsigned short W3T[256 * 64];
    __shared__ unsigned short h1s[8][16 * 64];
    __shared__ unsigned short h2s[8][16 * 64];
    __shared__ unsigned short wTs[8][256 * 20];

    const int tid = threadIdx.x;
    for (int i = tid; i < 64 * 64; i += 512) {
        int k = i >> 6, n = i & 63;
        W2T[swz128(n, 2 * k) >> 1] = f2bf(W2[i]);
    }
    for (int i = tid; i < 256 * 64; i += 512) {
        int k = i >> 8, n = i & 255;
        W3T[swz128(n, 2 * k) >> 1] = f2bf(W3[i]);
    }
    __syncthreads();

    const int lane = tid & 63;
    const int wvi = tid >> 6;
    const int l15 = lane & 15;
    const int g = lane >> 4;

    float w1r[8];
#pragma unroll
    for (int r = 0; r < 8; ++r) w1r[r] = W1[(r << 6) | lane];

    unsigned short* h1w = h1s[wvi];
    unsigned short* h2w = h2s[wvi];
    unsigned short* wTw = wTs[wvi];

    for (int t = blockIdx.x; t < kE / 128; t += gridDim.x) {
        const int et = t * 128 + wvi * 16;

        // ---- per-lane edge scalars for edge et + l15 (broadcast in Phase D);
        //      issued early so the loads overlap Phases A-C ----
        const int eidL = et + l15;
        const int sidL = snd[eidL];
        const int pL = off[rcv[eidL]] + pos[eidL];
        const float exL = ev[(size_t)eidL * 3 + 0];
        const float eyL = ev[(size_t)eidL * 3 + 1];
        const float ezL = ev[(size_t)eidL * 3 + 2];
        const float riL = rsqrtf(exL * exL + eyL * eyL + ezL * ezL + 1e-12f);
        const float y0L = 1.7320508075688772f * exL * riL;
        const float y1L = 1.7320508075688772f * eyL * riL;
        const float y2L = 1.7320508075688772f * ezL * riL;

        for (int e = 0; e < 16; ++e) {
            const float4 ra = *(const float4*)&rad[(size_t)(et + e) * 8];
            const float4 rb = *(const float4*)&rad[(size_t)(et + e) * 8 + 4];
            float acc = ra.x * w1r[0] + ra.y * w1r[1] + ra.z * w1r[2] + ra.w * w1r[3]
                      + rb.x * w1r[4] + rb.y * w1r[5] + rb.z * w1r[6] + rb.w * w1r[7];
            h1w[swz128(e, 2 * lane) >> 1] = f2bf(silu_f(acc));
        }
        __builtin_amdgcn_wave_barrier();

        bf16x8 a0 = *(const bf16x8*)&h1w[swz128(l15, g * 16) >> 1];
        bf16x8 a1 = *(const bf16x8*)&h1w[swz128(l15, 64 + g * 16) >> 1];

#pragma unroll
        for (int n0 = 0; n0 < 64; n0 += 16) {
            const int n = n0 + l15;
            bf16x8 b0 = *(const bf16x8*)&W2T[swz128(n, g * 16) >> 1];
            bf16x8 b1 = *(const bf16x8*)&W2T[swz128(n, 64 + g * 16) >> 1];
            f32x4 acc = {0.f, 0.f, 0.f, 0.f};
            acc = __builtin_amdgcn_mfma_f32_16x16x32_bf16(a0, b0, acc, 0, 0, 0);
            acc = __builtin_amdgcn_mfma_f32_16x16x32_bf16(a1, b1, acc, 0, 0, 0);
#pragma unroll
            for (int r = 0; r < 4; ++r) {
                int e2 = g * 4 + r;
                h2w[swz128(e2, 2 * n) >> 1] = f2bf(silu_f(acc[r]));
            }
        }
        __builtin_amdgcn_wave_barrier();

        bf16x8 c0 = *(const bf16x8*)&h2w[swz128(l15, g * 16) >> 1];
        bf16x8 c1 = *(const bf16x8*)&h2w[swz128(l15, 64 + g * 16) >> 1];
#pragma unroll
        for (int m0 = 0; m0 < 16; ++m0) {
            const int nrow = m0 * 16 + l15;
            bf16x8 wa0 = *(const bf16x8*)&W3T[swz128(nrow, g * 16) >> 1];
            bf16x8 wa1 = *(const bf16x8*)&W3T[swz128(nrow, 64 + g * 16) >> 1];
            f32x4 acc = {0.f, 0.f, 0.f, 0.f};
            acc = __builtin_amdgcn_mfma_f32_16x16x32_bf16(wa0, c0, acc, 0, 0, 0);
            acc = __builtin_amdgcn_mfma_f32_16x16x32_bf16(wa1, c1, acc, 0, 0, 0);
#pragma unroll
            for (int r = 0; r < 4; ++r) {
                int nn = m0 * 16 + g * 4 + r;
                wTw[nn * 20 + l15] = f2bf(acc[r]);
            }
        }
        __builtin_amdgcn_wave_barrier();

        const int c = lane;
#pragma unroll
        for (int grp = 0; grp < 4; ++grp) {
            ushort4 qa[4];
#pragma unroll
            for (int k = 0; k < 4; ++k)
                qa[k] = *(const ushort4*)&wTw[(k * 64 + c) * 20 + grp * 4];
            const unsigned short* qp = (const unsigned short*)qa;
#pragma unroll
            for (int e = 0; e < 4; ++e) {
                const int idx = grp * 4 + e;
                const int sid = __shfl(sidL, idx, 64);
                const int p = __shfl(pL, idx, 64);
                const float y0 = __shfl(y0L, idx, 64);
                const float y1 = __shfl(y1L, idx, 64);
                const float y2 = __shfl(y2L, idx, 64);
                const float4 xv = *(const float4*)&nf[(((size_t)sid << 6) | c) << 2];
                const float w0 = bf2f(qp[0 * 4 + e]);
                const float w1 = bf2f(qp[1 * 4 + e]);
                const float w2v = bf2f(qp[2 * 4 + e]);
                const float w3v = bf2f(qp[3 * 4 + e]);
                const float dot1 = xv.y * y0 + xv.z * y1 + xv.w * y2;
                const float m0v = w0 * xv.x + w1 * dot1;
                const float t2 = w2v * xv.x;
                ushort4 q;
                q.x = f2bf(m0v);
                q.y = f2bf(t2 * y0 + w3v * xv.y);
                q.z = f2bf(t2 * y1 + w3v * xv.z);
                q.w = f2bf(t2 * y2 + w3v * xv.w);
                *(ushort4*)&mq[((size_t)p << 8) + (c << 2)] = q;
            }
        }
        __builtin_amdgcn_wave_barrier();
    }
}

// ---------------------------------------------------------------------------
// node_mfma (v14, unchanged): block (4 waves) per 16-node tile; hi/lo slab,
// 8-deep gather ILP.
// ---------------------------------------------------------------------------
__global__ __launch_bounds__(256, 2)
void node_mfma(const float* __restrict__ nf, const int* __restrict__ spc,
               const unsigned short* __restrict__ WlT0, const unsigned short* __restrict__ WlT1,
               const unsigned short* __restrict__ WpT0, const unsigned short* __restrict__ WpT1,
               const unsigned short* __restrict__ WrT0, const unsigned short* __restrict__ WrT1,
               const float* __restrict__ Wsc0, const float* __restrict__ Wsc1,
               const float* __restrict__ Wrd,
               const unsigned short* __restrict__ m, const int* __restrict__ off,
               const int* __restrict__ nidx,
               float* __restrict__ out0, float* __restrict__ outF)
{
    __shared__ unsigned short slab[8][1024];   // planes 0-3 hi, 4-7 lo (16 KB)
    __shared__ float roS[4][16];

    const int tid = threadIdx.x;
    const int lane = tid & 63;
    const int wvi = tid >> 6;
    const int l15 = lane & 15;
    const int g = lane >> 4;
    const int tb = (int)blockIdx.x << 4;

    const int c = lane;
    for (int e4 = 0; e4 < 4; ++e4) {
        const int e = wvi * 4 + e4;
        const int node = nidx[tb + e];
        float ax = 0.f, ay = 0.f, az = 0.f, aw = 0.f;
        if (node >= 0) {
            const int beg = off[node], end = off[node + 1];
            int i = beg;
            for (; i + 8 <= end; i += 8) {
                const ushort4 q0 = *(const ushort4*)&m[((size_t)(i + 0) << 8) + (c << 2)];
                const ushort4 q1 = *(const ushort4*)&m[((size_t)(i + 1) << 8) + (c << 2)];
                const ushort4 q2 = *(const ushort4*)&m[((size_t)(i + 2) << 8) + (c << 2)];
                const ushort4 q3 = *(const ushort4*)&m[((size_t)(i + 3) << 8) + (c << 2)];
                const ushort4 q4 = *(const ushort4*)&m[((size_t)(i + 4) << 8) + (c << 2)];
                const ushort4 q5 = *(const ushort4*)&m[((size_t)(i + 5) << 8) + (c << 2)];
                const ushort4 q6 = *(const ushort4*)&m[((size_t)(i + 6) << 8) + (c << 2)];
                const ushort4 q7 = *(const ushort4*)&m[((size_t)(i + 7) << 8) + (c << 2)];
                ax += ((bf2f(q0.x) + bf2f(q1.x)) + (bf2f(q2.x) + bf2f(q3.x)))
                    + ((bf2f(q4.x) + bf2f(q5.x)) + (bf2f(q6.x) + bf2f(q7.x)));
                ay += ((bf2f(q0.y) + bf2f(q1.y)) + (bf2f(q2.y) + bf2f(q3.y)))
                    + ((bf2f(q4.y) + bf2f(q5.y)) + (bf2f(q6.y) + bf2f(q7.y)));
                az += ((bf2f(q0.z) + bf2f(q1.z)) + (bf2f(q2.z) + bf2f(q3.z)))
                    + ((bf2f(q4.z) + bf2f(q5.z)) + (bf2f(q6.z) + bf2f(q7.z)));
                aw += ((bf2f(q0.w) + bf2f(q1.w)) + (bf2f(q2.w) + bf2f(q3.w)))
                    + ((bf2f(q4.w) + bf2f(q5.w)) + (bf2f(q6.w) + bf2f(q7.w)));
            }
            for (; i + 4 <= end; i += 4) {
                const ushort4 q0 = *(const ushort4*)&m[((size_t)(i + 0) << 8) + (c << 2)];
                const ushort4 q1 = *(const ushort4*)&m[((size_t)(i + 1) << 8) + (c << 2)];
                const ushort4 q2 = *(const ushort4*)&m[((size_t)(i + 2) << 8) + (c << 2)];
                const ushort4 q3 = *(const ushort4*)&m[((size_t)(i + 3) << 8) + (c << 2)];
                ax += (bf2f(q0.x) + bf2f(q1.x)) + (bf2f(q2.x) + bf2f(q3.x));
                ay += (bf2f(q0.y) + bf2f(q1.y)) + (bf2f(q2.y) + bf2f(q3.y));
                az += (bf2f(q0.z) + bf2f(q1.z)) + (bf2f(q2.z) + bf2f(q3.z));
                aw += (bf2f(q0.w) + bf2f(q1.w)) + (bf2f(q2.w) + bf2f(q3.w));
            }
            for (; i < end; ++i) {
                const ushort4 q = *(const ushort4*)&m[((size_t)i << 8) + (c << 2)];
                ax += bf2f(q.x); ay += bf2f(q.y); az += bf2f(q.z); aw += bf2f(q.w);
            }
        }
        const float vv[4] = {ax * 0.125f, ay * 0.125f, az * 0.125f, aw * 0.125f};
        const int o = swz128(e, 2 * c) >> 1;
#pragma unroll
        for (int p = 0; p < 4; ++p) {
            const unsigned short hi = f2bf1(vv[p]);
            slab[p][o] = hi;
            slab[4 + p][o] = f2bf1(vv[p] - bf2f(hi));
        }
    }
    __syncthreads();

    const int n0 = nidx[tb];
    if (n0 < 0) return;
    const int s = spc[n0];

    bf16x8 aF[8][2];
#pragma unroll
    for (int p = 0; p < 8; ++p) {
        aF[p][0] = *(const bf16x8*)&slab[p][swz128(l15, g * 16) >> 1];
        aF[p][1] = *(const bf16x8*)&slab[p][swz128(l15, 64 + g * 16) >> 1];
    }
    __syncthreads();

    const int d = l15 + 16 * wvi;
    {
        bf16x8 bl0a = *(const bf16x8*)&WlT0[swz128(d, g * 16) >> 1];
        bf16x8 bl0b = *(const bf16x8*)&WlT0[swz128(d, 64 + g * 16) >> 1];
        bf16x8 bl1a = *(const bf16x8*)&WlT1[swz128(d, g * 16) >> 1];
        bf16x8 bl1b = *(const bf16x8*)&WlT1[swz128(d, 64 + g * 16) >> 1];
        f32x4 A0v = {0.f, 0.f, 0.f, 0.f};
        f32x4 Axv = {0.f, 0.f, 0.f, 0.f};
        f32x4 Ayv = {0.f, 0.f, 0.f, 0.f};
        f32x4 Azv = {0.f, 0.f, 0.f, 0.f};
        A0v = __builtin_amdgcn_mfma_f32_16x16x32_bf16(aF[0][0], bl0a, A0v, 0, 0, 0);
        A0v = __builtin_amdgcn_mfma_f32_16x16x32_bf16(aF[0][1], bl0b, A0v, 0, 0, 0);
        A0v = __builtin_amdgcn_mfma_f32_16x16x32_bf16(aF[4][0], bl0a, A0v, 0, 0, 0);
        A0v = __builtin_amdgcn_mfma_f32_16x16x32_bf16(aF[4][1], bl0b, A0v, 0, 0, 0);
        Axv = __builtin_amdgcn_mfma_f32_16x16x32_bf16(aF[1][0], bl1a, Axv, 0, 0, 0);
        Axv = __builtin_amdgcn_mfma_f32_16x16x32_bf16(aF[1][1], bl1b, Axv, 0, 0, 0);
        Axv = __builtin_amdgcn_mfma_f32_16x16x32_bf16(aF[5][0], bl1a, Axv, 0, 0, 0);
        Axv = __builtin_amdgcn_mfma_f32_16x16x32_bf16(aF[5][1], bl1b, Axv, 0, 0, 0);
        Ayv = __builtin_amdgcn_mfma_f32_16x16x32_bf16(aF[2][0], bl1a, Ayv, 0, 0, 0);
        Ayv = __builtin_amdgcn_mfma_f32_16x16x32_bf16(aF[2][1], bl1b, Ayv, 0, 0, 0);
        Ayv = __builtin_amdgcn_mfma_f32_16x16x32_bf16(aF[6][0], bl1a, Ayv, 0, 0, 0);
        Ayv = __builtin_amdgcn_mfma_f32_16x16x32_bf16(aF[6][1], bl1b, Ayv, 0, 0, 0);
        Azv = __builtin_amdgcn_mfma_f32_16x16x32_bf16(aF[3][0], bl1a, Azv, 0, 0, 0);
        Azv = __builtin_amdgcn_mfma_f32_16x16x32_bf16(aF[3][1], bl1b, Azv, 0, 0, 0);
        Azv = __builtin_amdgcn_mfma_f32_16x16x32_bf16(aF[7][0], bl1a, Azv, 0, 0, 0);
        Azv = __builtin_amdgcn_mfma_f32_16x16x32_bf16(aF[7][1], bl1b, Azv, 0, 0, 0);

        const float* w0p = &Wsc0[((s << 6) | d) * 5];
        const float c0 = w0p[0], c1 = w0p[1], c2 = w0p[2], c3 = w0p[3], c4 = w0p[4];
        const float4 w1v = *(const float4*)&Wsc1[((s << 6) | d) << 2];

#pragma unroll
        for (int r = 0; r < 4; ++r) {
            const float A0 = A0v[r], Ax = Axv[r], Ay = Ayv[r], Az = Azv[r];
            const float n1 = Ax * Ax + Ay * Ay + Az * Az;
            const float A0sq = A0 * A0;
            const float B0 = c0 * A0 + c1 * A0sq + c2 * A0sq * A0 + c3 * n1 + c4 * A0 * n1;
            const float gg = w1v.x + w1v.y * A0 + w1v.z * A0sq + w1v.w * n1;
            const float bb[4] = {B0, gg * Ax, gg * Ay, gg * Az};
            const int o = swz128(g * 4 + r, 2 * d) >> 1;
#pragma unroll
            for (int p = 0; p < 4; ++p) {
                const unsigned short hi = f2bf1(bb[p]);
                slab[p][o] = hi;
                slab[4 + p][o] = f2bf1(bb[p] - bf2f(hi));
            }
        }
    }
    __syncthreads();

    bf16x8 bF[8][2];
#pragma unroll
    for (int p = 0; p < 8; ++p) {
        bF[p][0] = *(const bf16x8*)&slab[p][swz128(l15, g * 16) >> 1];
        bF[p][1] = *(const bf16x8*)&slab[p][swz128(l15, 64 + g * 16) >> 1];
    }
    const int xnode = nidx[tb + l15];
    bf16x8 xF[4][2];
#pragma unroll
    for (int h = 0; h < 2; ++h) {
#pragma unroll
        for (int j = 0; j < 8; ++j) {
            const int k = h * 32 + g * 8 + j;
            float4 v = make_float4(0.f, 0.f, 0.f, 0.f);
            if (xnode >= 0) v = *(const float4*)&nf[(((size_t)xnode << 6) | k) << 2];
            xF[0][h][j] = (short)f2bf1(v.x);
            xF[1][h][j] = (short)f2bf1(v.y);
            xF[2][h][j] = (short)f2bf1(v.z);
            xF[3][h][j] = (short)f2bf1(v.w);
        }
    }

    const int ndr0 = nidx[tb + g * 4 + 0];
    const int ndr1 = nidx[tb + g * 4 + 1];
    const int ndr2 = nidx[tb + g * 4 + 2];
    const int ndr3 = nidx[tb + g * 4 + 3];

    {
        bf16x8 bp0a = *(const bf16x8*)&WpT0[swz128(d, g * 16) >> 1];
        bf16x8 bp0b = *(const bf16x8*)&WpT0[swz128(d, 64 + g * 16) >> 1];
        bf16x8 bp1a = *(const bf16x8*)&WpT1[swz128(d, g * 16) >> 1];
        bf16x8 bp1b = *(const bf16x8*)&WpT1[swz128(d, 64 + g * 16) >> 1];
        const unsigned short* wr0 = &WrT0[(size_t)s << 12];
        const unsigned short* wr1 = &WrT1[(size_t)s << 12];
        bf16x8 br0a = *(const bf16x8*)&wr0[swz128(d, g * 16) >> 1];
        bf16x8 br0b = *(const bf16x8*)&wr0[swz128(d, 64 + g * 16) >> 1];
        bf16x8 br1a = *(const bf16x8*)&wr1[swz128(d, g * 16) >> 1];
        bf16x8 br1b = *(const bf16x8*)&wr1[swz128(d, 64 + g * 16) >> 1];

        f32x4 F0v = {0.f, 0.f, 0.f, 0.f};
        f32x4 Fxv = {0.f, 0.f, 0.f, 0.f};
        f32x4 Fyv = {0.f, 0.f, 0.f, 0.f};
        f32x4 Fzv = {0.f, 0.f, 0.f, 0.f};
        F0v = __builtin_amdgcn_mfma_f32_16x16x32_bf16(bF[0][0], bp0a, F0v, 0, 0, 0);
        F0v = __builtin_amdgcn_mfma_f32_16x16x32_bf16(bF[0][1], bp0b, F0v, 0, 0, 0);
        F0v = __builtin_amdgcn_mfma_f32_16x16x32_bf16(bF[4][0], bp0a, F0v, 0, 0, 0);
        F0v = __builtin_amdgcn_mfma_f32_16x16x32_bf16(bF[4][1], bp0b, F0v, 0, 0, 0);
        F0v = __builtin_amdgcn_mfma_f32_16x16x32_bf16(xF[0][0], br0a, F0v, 0, 0, 0);
        F0v = __builtin_amdgcn_mfma_f32_16x16x32_bf16(xF[0][1], br0b, F0v, 0, 0, 0);
        Fxv = __builtin_amdgcn_mfma_f32_16x16x32_bf16(bF[1][0], bp1a, Fxv, 0, 0, 0);
        Fxv = __builtin_amdgcn_mfma_f32_16x16x32_bf16(bF[1][1], bp1b, Fxv, 0, 0, 0);
        Fxv = __builtin_amdgcn_mfma_f32_16x16x32_bf16(bF[5][0], bp1a, Fxv, 0, 0, 0);
        Fxv = __builtin_amdgcn_mfma_f32_16x16x32_bf16(bF[5][1], bp1b, Fxv, 0, 0, 0);
        Fxv = __builtin_amdgcn_mfma_f32_16x16x32_bf16(xF[1][0], br1a, Fxv, 0, 0, 0);
        Fxv = __builtin_amdgcn_mfma_f32_16x16x32_bf16(xF[1][1], br1b, Fxv, 0, 0, 0);
        Fyv = __builtin_amdgcn_mfma_f32_16x16x32_bf16(bF[2][0], bp1a, Fyv, 0, 0, 0);
        Fyv = __builtin_amdgcn_mfma_f32_16x16x32_bf16(bF[2][1], bp1b, Fyv, 0, 0, 0);
        Fyv = __builtin_amdgcn_mfma_f32_16x16x32_bf16(bF[6][0], bp1a, Fyv, 0, 0, 0);
        Fyv = __builtin_amdgcn_mfma_f32_16x16x32_bf16(bF[6][1], bp1b, Fyv, 0, 0, 0);
        Fyv = __builtin_amdgcn_mfma_f32_16x16x32_bf16(xF[2][0], br1a, Fyv, 0, 0, 0);
        Fyv = __builtin_amdgcn_mfma_f32_16x16x32_bf16(xF[2][1], br1b, Fyv, 0, 0, 0);
        Fzv = __builtin_amdgcn_mfma_f32_16x16x32_bf16(bF[3][0], bp1a, Fzv, 0, 0, 0);
        Fzv = __builtin_amdgcn_mfma_f32_16x16x32_bf16(bF[3][1], bp1b, Fzv, 0, 0, 0);
        Fzv = __builtin_amdgcn_mfma_f32_16x16x32_bf16(bF[7][0], bp1a, Fzv, 0, 0, 0);
        Fzv = __builtin_amdgcn_mfma_f32_16x16x32_bf16(bF[7][1], bp1b, Fzv, 0, 0, 0);
        Fzv = __builtin_amdgcn_mfma_f32_16x16x32_bf16(xF[3][0], br1a, Fzv, 0, 0, 0);
        Fzv = __builtin_amdgcn_mfma_f32_16x16x32_bf16(xF[3][1], br1b, Fzv, 0, 0, 0);

        const float wdv = Wrd[d];
        if (ndr0 >= 0) *(float4*)&outF[((size_t)ndr0 << 8) + (d << 2)] = make_float4(F0v[0], Fxv[0], Fyv[0], Fzv[0]);
        if (ndr1 >= 0) *(float4*)&outF[((size_t)ndr1 << 8) + (d << 2)] = make_float4(F0v[1], Fxv[1], Fyv[1], Fzv[1]);
        if (ndr2 >= 0) *(float4*)&outF[((size_t)ndr2 << 8) + (d << 2)] = make_float4(F0v[2], Fxv[2], Fyv[2], Fzv[2]);
        if (ndr3 >= 0) *(float4*)&outF[((size_t)ndr3 << 8) + (d << 2)] = make_float4(F0v[3], Fxv[3], Fyv[3], Fzv[3]);

        float ro[4] = {F0v[0] * wdv, F0v[1] * wdv, F0v[2] * wdv, F0v[3] * wdv};
#pragma unroll
        for (int mo = 1; mo < 16; mo <<= 1) {
#pragma unroll
            for (int r = 0; r < 4; ++r) ro[r] += __shfl_xor(ro[r], mo, 64);
        }
        if (l15 == 0) {
#pragma unroll
            for (int r = 0; r < 4; ++r) roS[wvi][g * 4 + r] = ro[r];
        }
    }
    __syncthreads();

    if (tid < 16) {
        const int nd = nidx[tb + tid];
        if (nd >= 0)
            out0[nd] = roS[0][tid] + roS[1][tid] + roS[2][tid] + roS[3][tid];
    }
}

// ===========================================================================
extern "C" void kernel_launch(void* const* d_in, const int* in_sizes, int n_in,
                              void* d_out, int out_size, void* d_ws, size_t ws_size,
                              hipStream_t stream)
{
    const float* edge_vectors = (const float*)d_in[0];
    const float* node_feats   = (const float*)d_in[1];
    const int*   node_species = (const int*)d_in[2];
    const float* radial       = (const float*)d_in[3];
    const int*   senders      = (const int*)d_in[4];
    const int*   receivers    = (const int*)d_in[5];
    const float* W_r1   = (const float*)d_in[6];
    const float* W_r2   = (const float*)d_in[7];
    const float* W_r3   = (const float*)d_in[8];
    const float* W_lin0 = (const float*)d_in[9];
    const float* W_lin1 = (const float*)d_in[10];
    const float* Wsc0   = (const float*)d_in[11];
    const float* Wsc1   = (const float*)d_in[12];
    const float* Wp0    = (const float*)d_in[13];
    const float* Wp1    = (const float*)d_in[14];
    const float* Wres0  = (const float*)d_in[15];
    const float* Wres1  = (const float*)d_in[16];
    const float* W_read = (const float*)d_in[17];

    float* out0 = (float*)d_out;
    float* outF = out0 + kN;

    char* ws = (char*)d_ws;
    unsigned short* m = (unsigned short*)(ws + kOffM);
    int* cnt  = (int*)(ws + kOffCnt);
    int* cnt2 = (int*)(ws + kOffCnt2);
    int* off  = (int*)(ws + kOffOff);
    int* off2 = (int*)(ws + kOffOff2);
    int* cur  = (int*)(ws + kOffCur);
    int* cur2 = (int*)(ws + kOffCur2);
    int* pos  = (int*)(ws + kOffPos);
    int* nidx = (int*)(ws + kOffNidx);
    unsigned short* WlT0 = (unsigned short*)(ws + kOffWlT0);
    unsigned short* WlT1 = (unsigned short*)(ws + kOffWlT1);
    unsigned short* WpT0 = (unsigned short*)(ws + kOffWpT0);
    unsigned short* WpT1 = (unsigned short*)(ws + kOffWpT1);
    unsigned short* WrT0 = (unsigned short*)(ws + kOffWrT0);
    unsigned short* WrT1 = (unsigned short*)(ws + kOffWrT1);

    hipMemsetAsync(cnt, 0, kN * sizeof(int) + 64, stream);
    hipMemsetAsync(nidx, 0xFF, (size_t)kTilesMax * 16 * sizeof(int), stream);

    prep_kernel<<<1024, 256, 0, stream>>>(receivers, node_species,
                                          W_lin0, W_lin1, Wp0, Wp1, Wres0, Wres1,
                                          cnt, cnt2, pos,
                                          WlT0, WlT1, WpT0, WpT1, WrT0, WrT1);
    scan_kernel<<<1, 1024, 0, stream>>>(cnt, off, cur, cnt2, off2, cur2);
    rank_kernel<<<1024, 256, 0, stream>>>(node_species, cur2, nidx);

    edge_mfma<<<256, 512, 0, stream>>>(edge_vectors, node_feats, radial,
                                       senders, receivers, off, pos,
                                       W_r1, W_r2, W_r3, m);

    node_mfma<<<kTilesMax, 256, 0, stream>>>(
        node_feats, node_species,
        WlT0, WlT1, WpT0, WpT1, WrT0, WrT1,
        Wsc0, Wsc1, W_read,
        m, off, nidx, out0, outF);
}

// Round 16
// 384.336 us; speedup vs baseline: 1.1162x; 1.0241x over previous
//
#include <hip/hip_runtime.h>

// MACE layer v16: v15 (passed, 393.6 us) + ONE change: f2bf manual RNE (5 ops)
// -> round-half-away (u + 0x8000) >> 16 (2 ops). ~160 converts/lane/iter in
// edge_mfma => ~25% VALU cut there. Ties-only numeric difference vs RNE.
// Everything else byte-identical to v15.

typedef __attribute__((ext_vector_type(8))) short bf16x8;
typedef __attribute__((ext_vector_type(4))) float f32x4;

constexpr int kN = 50000;
constexpr int kE = 400000;
constexpr int kS = 10;
constexpr int kTilesMax = 3150;

// ws layout (bytes)
constexpr size_t kOffM    = 0;           // kE*256 ushort = 204,800,000
constexpr size_t kOffCnt  = 204800000;   // kN int
constexpr size_t kOffCnt2 = 205000000;   // 16 int
constexpr size_t kOffOff  = 205000064;   // kN+1 int
constexpr size_t kOffOff2 = 205200128;   // 16 int
constexpr size_t kOffCur  = 205200192;   // kN int
constexpr size_t kOffCur2 = 205400192;   // 16 int
constexpr size_t kOffPos  = 205400256;   // kE int (local rank within segment)
constexpr size_t kOffNidx = 207000256;   // kTilesMax*16 int
constexpr size_t kOffWlT0 = 207201856;   // 4096 ushort each
constexpr size_t kOffWlT1 = 207210048;
constexpr size_t kOffWpT0 = 207218240;
constexpr size_t kOffWpT1 = 207226432;
constexpr size_t kOffWrT0 = 207234624;   // 10*4096 ushort
constexpr size_t kOffWrT1 = 207316544;   // end 207,398,464

__device__ __forceinline__ float silu_f(float x) {
    float t = __expf(-x);
    return x / (1.0f + t);
}
// f32->bf16 round-half-away (2 ops; ties-only difference vs RNE).
// Do NOT replace with cvt_pk asm in the edge kernel (r10 NaN).
__device__ __forceinline__ unsigned short f2bf(float f) {
    return (unsigned short)((__float_as_uint(f) + 0x8000u) >> 16);
}
// cvt_pk helpers (node path only — proven there)
__device__ __forceinline__ unsigned cvt_pk_bf16(float lo, float hi) {
    unsigned r;
    asm("v_cvt_pk_bf16_f32 %0, %1, %2" : "=v"(r) : "v"(lo), "v"(hi));
    return r;
}
__device__ __forceinline__ unsigned short f2bf1(float x) {
    return (unsigned short)cvt_pk_bf16(x, 0.f);
}
__device__ __forceinline__ float bf2f(unsigned short b) {
    return __uint_as_float(((unsigned)b) << 16);
}
__device__ __forceinline__ int swz128(int row, int byteoff) {
    return row * 128 + (byteoff ^ ((row & 7) << 4));
}

// ---------------------------------------------------------------------------
// prep: edge hist stores local rank -> pos; species hist (LDS-agg); weights
// ---------------------------------------------------------------------------
__global__ __launch_bounds__(256)
void prep_kernel(const int* __restrict__ rcv, const int* __restrict__ spc,
                 const float* __restrict__ Wl0, const float* __restrict__ Wl1,
                 const float* __restrict__ Wp0, const float* __restrict__ Wp1,
                 const float* __restrict__ Wres0, const float* __restrict__ Wres1,
                 int* __restrict__ cnt, int* __restrict__ cnt2,
                 int* __restrict__ pos,
                 unsigned short* __restrict__ WlT0, unsigned short* __restrict__ WlT1,
                 unsigned short* __restrict__ WpT0, unsigned short* __restrict__ WpT1,
                 unsigned short* __restrict__ WrT0, unsigned short* __restrict__ WrT1)
{
    const int tid = threadIdx.x;
    const int gtid = blockIdx.x * 256 + tid;
    const int gstride = gridDim.x * 256;

    for (int i = gtid; i < kE; i += gstride) pos[i] = atomicAdd(&cnt[rcv[i]], 1);

    __shared__ int lh[kS];
    for (int base = blockIdx.x * 256; base < kN; base += gstride) {
        if (tid < kS) lh[tid] = 0;
        __syncthreads();
        int node = base + tid;
        if (node < kN) atomicAdd(&lh[spc[node]], 1);
        __syncthreads();
        if (tid < kS && lh[tid]) atomicAdd(&cnt2[tid], lh[tid]);
        __syncthreads();
    }

    for (int i3 = gtid; i3 < 16384 + 81920; i3 += gstride) {
        if (i3 < 16384) {
            int w = i3 >> 12, r = i3 & 4095, k = r >> 6, n = r & 63;
            const float* src = (w == 0) ? Wl0 : (w == 1) ? Wl1 : (w == 2) ? Wp0 : Wp1;
            unsigned short* dst = (w == 0) ? WlT0 : (w == 1) ? WlT1 : (w == 2) ? WpT0 : WpT1;
            dst[swz128(n, 2 * k) >> 1] = f2bf(src[r]);
        } else {
            int i4 = i3 - 16384;
            int w = i4 / 40960;
            int r5 = i4 - w * 40960;                 // s*4096 + c*64 + d
            int s = r5 >> 12, r = r5 & 4095, k = r >> 6, n = r & 63;
            const float* src = w ? Wres1 : Wres0;
            unsigned short* dst = w ? WrT1 : WrT0;
            dst[(s << 12) + (swz128(n, 2 * k) >> 1)] = f2bf(src[r5]);
        }
    }
}

// ---------------------------------------------------------------------------
__global__ __launch_bounds__(1024)
void scan_kernel(const int* __restrict__ cnt, int* __restrict__ off,
                 int* __restrict__ cur,
                 const int* __restrict__ cnt2, int* __restrict__ off2,
                 int* __restrict__ cur2)
{
    __shared__ int wred[16];
    const int tid = threadIdx.x;
    const int lane = tid & 63;
    const int wv = tid >> 6;
    const int CH = 49;
    const int b = tid * CH;
    int s = 0;
    for (int i = 0; i < CH; ++i) {
        int idx = b + i;
        if (idx < kN) s += cnt[idx];
    }
    int incl = s;
    for (int d = 1; d < 64; d <<= 1) {
        int t = __shfl_up(incl, d, 64);
        if (lane >= d) incl += t;
    }
    if (lane == 63) wred[wv] = incl;
    __syncthreads();
    if (tid < 16) {
        int o = wred[tid];
        int v = o;
        for (int d = 1; d < 16; d <<= 1) {
            int t = __shfl_up(v, d, 64);
            if (tid >= d) v += t;
        }
        wred[tid] = v - o;
    }
    __syncthreads();
    int run = wred[wv] + (incl - s);
    for (int i = 0; i < CH; ++i) {
        int idx = b + i;
        if (idx < kN) {
            int c = cnt[idx];
            off[idx] = run;
            cur[idx] = run;
            run += c;
        }
    }
    if (tid == 0) {
        off[kN] = kE;
        int base = 0;
        for (int sp = 0; sp < kS; ++sp) {
            off2[sp] = base;
            cur2[sp] = base;
            base += (cnt2[sp] + 15) & ~15;
        }
        off2[kS] = base;
    }
}

// ---------------------------------------------------------------------------
__global__ __launch_bounds__(256)
void rank_kernel(const int* __restrict__ spc,
                 int* __restrict__ cur2, int* __restrict__ nidx)
{
    const int tid = threadIdx.x;
    const int gstride = gridDim.x * 256;

    __shared__ int lh[kS];
    __shared__ int gbase[kS];
    for (int base = blockIdx.x * 256; base < kN; base += gstride) {
        if (tid < kS) lh[tid] = 0;
        __syncthreads();
        const int node = base + tid;
        int s = -1, lr = 0;
        if (node < kN) {
            s = spc[node];
            lr = atomicAdd(&lh[s], 1);
        }
        __syncthreads();
        if (tid < kS) gbase[tid] = lh[tid] ? atomicAdd(&cur2[tid], lh[tid]) : 0;
        __syncthreads();
        if (node < kN) nidx[gbase[s] + lr] = node;
        __syncthreads();
    }
}

// ---------------------------------------------------------------------------
// edge_mfma (v15, unchanged structure). 512 thr (8 waves), 16 edges/wave.
// ---------------------------------------------------------------------------
__global__ __launch_bounds__(512, 1)
void edge_mfma(const float* __restrict__ ev,
               const float* __restrict__ nf,
               const float* __restrict__ rad,
               const int* __restrict__ snd,
               const int* __restrict__ rcv,
               const int* __restrict__ off,
               const int* __restrict__ pos,
               const float* __restrict__ W1,
               const float* __restrict__ W2,
               const float* __restrict__ W3,
               unsigned short* __restrict__ mq)
{
    __shared__ unsigned short W2T[64 * 64];
    __shared__ unsigned short W3T[256 * 64];
    __shared__ unsigned short h1s[8][16 * 64];
    __shared__ unsigned short h2s[8][16 * 64];
    __shared__ unsigned short wTs[8][256 * 20];

    const int tid = threadIdx.x;
    for (int i = tid; i < 64 * 64; i += 512) {
        int k = i >> 6, n = i & 63;
        W2T[swz128(n, 2 * k) >> 1] = f2bf(W2[i]);
    }
    for (int i = tid; i < 256 * 64; i += 512) {
        int k = i >> 8, n = i & 255;
        W3T[swz128(n, 2 * k) >> 1] = f2bf(W3[i]);
    }
    __syncthreads();

    const int lane = tid & 63;
    const int wvi = tid >> 6;
    const int l15 = lane & 15;
    const int g = lane >> 4;

    float w1r[8];
#pragma unroll
    for (int r = 0; r < 8; ++r) w1r[r] = W1[(r << 6) | lane];

    unsigned short* h1w = h1s[wvi];
    unsigned short* h2w = h2s[wvi];
    unsigned short* wTw = wTs[wvi];

    for (int t = blockIdx.x; t < kE / 128; t += gridDim.x) {
        const int et = t * 128 + wvi * 16;

        // per-lane edge scalars for edge et + l15 (broadcast in Phase D)
        const int eidL = et + l15;
        const int sidL = snd[eidL];
        const int pL = off[rcv[eidL]] + pos[eidL];
        const float exL = ev[(size_t)eidL * 3 + 0];
        const float eyL = ev[(size_t)eidL * 3 + 1];
        const float ezL = ev[(size_t)eidL * 3 + 2];
        const float riL = rsqrtf(exL * exL + eyL * eyL + ezL * ezL + 1e-12f);
        const float y0L = 1.7320508075688772f * exL * riL;
        const float y1L = 1.7320508075688772f * eyL * riL;
        const float y2L = 1.7320508075688772f * ezL * riL;

        for (int e = 0; e < 16; ++e) {
            const float4 ra = *(const float4*)&rad[(size_t)(et + e) * 8];
            const float4 rb = *(const float4*)&rad[(size_t)(et + e) * 8 + 4];
            float acc = ra.x * w1r[0] + ra.y * w1r[1] + ra.z * w1r[2] + ra.w * w1r[3]
                      + rb.x * w1r[4] + rb.y * w1r[5] + rb.z * w1r[6] + rb.w * w1r[7];
            h1w[swz128(e, 2 * lane) >> 1] = f2bf(silu_f(acc));
        }
        __builtin_amdgcn_wave_barrier();

        bf16x8 a0 = *(const bf16x8*)&h1w[swz128(l15, g * 16) >> 1];
        bf16x8 a1 = *(const bf16x8*)&h1w[swz128(l15, 64 + g * 16) >> 1];

#pragma unroll
        for (int n0 = 0; n0 < 64; n0 += 16) {
            const int n = n0 + l15;
            bf16x8 b0 = *(const bf16x8*)&W2T[swz128(n, g * 16) >> 1];
            bf16x8 b1 = *(const bf16x8*)&W2T[swz128(n, 64 + g * 16) >> 1];
            f32x4 acc = {0.f, 0.f, 0.f, 0.f};
            acc = __builtin_amdgcn_mfma_f32_16x16x32_bf16(a0, b0, acc, 0, 0, 0);
            acc = __builtin_amdgcn_mfma_f32_16x16x32_bf16(a1, b1, acc, 0, 0, 0);
#pragma unroll
            for (int r = 0; r < 4; ++r) {
                int e2 = g * 4 + r;
                h2w[swz128(e2, 2 * n) >> 1] = f2bf(silu_f(acc[r]));
            }
        }
        __builtin_amdgcn_wave_barrier();

        bf16x8 c0 = *(const bf16x8*)&h2w[swz128(l15, g * 16) >> 1];
        bf16x8 c1 = *(const bf16x8*)&h2w[swz128(l15, 64 + g * 16) >> 1];
#pragma unroll
        for (int m0 = 0; m0 < 16; ++m0) {
            const int nrow = m0 * 16 + l15;
            bf16x8 wa0 = *(const bf16x8*)&W3T[swz128(nrow, g * 16) >> 1];
            bf16x8 wa1 = *(const bf16x8*)&W3T[swz128(nrow, 64 + g * 16) >> 1];
            f32x4 acc = {0.f, 0.f, 0.f, 0.f};
            acc = __builtin_amdgcn_mfma_f32_16x16x32_bf16(wa0, c0, acc, 0, 0, 0);
            acc = __builtin_amdgcn_mfma_f32_16x16x32_bf16(wa1, c1, acc, 0, 0, 0);
#pragma unroll
            for (int r = 0; r < 4; ++r) {
                int nn = m0 * 16 + g * 4 + r;
                wTw[nn * 20 + l15] = f2bf(acc[r]);
            }
        }
        __builtin_amdgcn_wave_barrier();

        const int c = lane;
#pragma unroll
        for (int grp = 0; grp < 4; ++grp) {
            ushort4 qa[4];
#pragma unroll
            for (int k = 0; k < 4; ++k)
                qa[k] = *(const ushort4*)&wTw[(k * 64 + c) * 20 + grp * 4];
            const unsigned short* qp = (const unsigned short*)qa;
#pragma unroll
            for (int e = 0; e < 4; ++e) {
                const int idx = grp * 4 + e;
                const int sid = __shfl(sidL, idx, 64);
                const int p = __shfl(pL, idx, 64);
                const float y0 = __shfl(y0L, idx, 64);
                const float y1 = __shfl(y1L, idx, 64);
                const float y2 = __shfl(y2L, idx, 64);
                const float4 xv = *(const float4*)&nf[(((size_t)sid << 6) | c) << 2];
                const float w0 = bf2f(qp[0 * 4 + e]);
                const float w1 = bf2f(qp[1 * 4 + e]);
                const float w2v = bf2f(qp[2 * 4 + e]);
                const float w3v = bf2f(qp[3 * 4 + e]);
                const float dot1 = xv.y * y0 + xv.z * y1 + xv.w * y2;
                const float m0v = w0 * xv.x + w1 * dot1;
                const float t2 = w2v * xv.x;
                ushort4 q;
                q.x = f2bf(m0v);
                q.y = f2bf(t2 * y0 + w3v * xv.y);
                q.z = f2bf(t2 * y1 + w3v * xv.z);
                q.w = f2bf(t2 * y2 + w3v * xv.w);
                *(ushort4*)&mq[((size_t)p << 8) + (c << 2)] = q;
            }
        }
        __builtin_amdgcn_wave_barrier();
    }
}

// ---------------------------------------------------------------------------
// node_mfma (v15, unchanged): block (4 waves) per 16-node tile; hi/lo slab,
// 8-deep gather ILP.
// ---------------------------------------------------------------------------
__global__ __launch_bounds__(256, 2)
void node_mfma(const float* __restrict__ nf, const int* __restrict__ spc,
               const unsigned short* __restrict__ WlT0, const unsigned short* __restrict__ WlT1,
               const unsigned short* __restrict__ WpT0, const unsigned short* __restrict__ WpT1,
               const unsigned short* __restrict__ WrT0, const unsigned short* __restrict__ WrT1,
               const float* __restrict__ Wsc0, const float* __restrict__ Wsc1,
               const float* __restrict__ Wrd,
               const unsigned short* __restrict__ m, const int* __restrict__ off,
               const int* __restrict__ nidx,
               float* __restrict__ out0, float* __restrict__ outF)
{
    __shared__ unsigned short slab[8][1024];   // planes 0-3 hi, 4-7 lo (16 KB)
    __shared__ float roS[4][16];

    const int tid = threadIdx.x;
    const int lane = tid & 63;
    const int wvi = tid >> 6;
    const int l15 = lane & 15;
    const int g = lane >> 4;
    const int tb = (int)blockIdx.x << 4;

    const int c = lane;
    for (int e4 = 0; e4 < 4; ++e4) {
        const int e = wvi * 4 + e4;
        const int node = nidx[tb + e];
        float ax = 0.f, ay = 0.f, az = 0.f, aw = 0.f;
        if (node >= 0) {
            const int beg = off[node], end = off[node + 1];
            int i = beg;
            for (; i + 8 <= end; i += 8) {
                const ushort4 q0 = *(const ushort4*)&m[((size_t)(i + 0) << 8) + (c << 2)];
                const ushort4 q1 = *(const ushort4*)&m[((size_t)(i + 1) << 8) + (c << 2)];
                const ushort4 q2 = *(const ushort4*)&m[((size_t)(i + 2) << 8) + (c << 2)];
                const ushort4 q3 = *(const ushort4*)&m[((size_t)(i + 3) << 8) + (c << 2)];
                const ushort4 q4 = *(const ushort4*)&m[((size_t)(i + 4) << 8) + (c << 2)];
                const ushort4 q5 = *(const ushort4*)&m[((size_t)(i + 5) << 8) + (c << 2)];
                const ushort4 q6 = *(const ushort4*)&m[((size_t)(i + 6) << 8) + (c << 2)];
                const ushort4 q7 = *(const ushort4*)&m[((size_t)(i + 7) << 8) + (c << 2)];
                ax += ((bf2f(q0.x) + bf2f(q1.x)) + (bf2f(q2.x) + bf2f(q3.x)))
                    + ((bf2f(q4.x) + bf2f(q5.x)) + (bf2f(q6.x) + bf2f(q7.x)));
                ay += ((bf2f(q0.y) + bf2f(q1.y)) + (bf2f(q2.y) + bf2f(q3.y)))
                    + ((bf2f(q4.y) + bf2f(q5.y)) + (bf2f(q6.y) + bf2f(q7.y)));
                az += ((bf2f(q0.z) + bf2f(q1.z)) + (bf2f(q2.z) + bf2f(q3.z)))
                    + ((bf2f(q4.z) + bf2f(q5.z)) + (bf2f(q6.z) + bf2f(q7.z)));
                aw += ((bf2f(q0.w) + bf2f(q1.w)) + (bf2f(q2.w) + bf2f(q3.w)))
                    + ((bf2f(q4.w) + bf2f(q5.w)) + (bf2f(q6.w) + bf2f(q7.w)));
            }
            for (; i + 4 <= end; i += 4) {
                const ushort4 q0 = *(const ushort4*)&m[((size_t)(i + 0) << 8) + (c << 2)];
                const ushort4 q1 = *(const ushort4*)&m[((size_t)(i + 1) << 8) + (c << 2)];
                const ushort4 q2 = *(const ushort4*)&m[((size_t)(i + 2) << 8) + (c << 2)];
                const ushort4 q3 = *(const ushort4*)&m[((size_t)(i + 3) << 8) + (c << 2)];
                ax += (bf2f(q0.x) + bf2f(q1.x)) + (bf2f(q2.x) + bf2f(q3.x));
                ay += (bf2f(q0.y) + bf2f(q1.y)) + (bf2f(q2.y) + bf2f(q3.y));
                az += (bf2f(q0.z) + bf2f(q1.z)) + (bf2f(q2.z) + bf2f(q3.z));
                aw += (bf2f(q0.w) + bf2f(q1.w)) + (bf2f(q2.w) + bf2f(q3.w));
            }
            for (; i < end; ++i) {
                const ushort4 q = *(const ushort4*)&m[((size_t)i << 8) + (c << 2)];
                ax += bf2f(q.x); ay += bf2f(q.y); az += bf2f(q.z); aw += bf2f(q.w);
            }
        }
        const float vv[4] = {ax * 0.125f, ay * 0.125f, az * 0.125f, aw * 0.125f};
        const int o = swz128(e, 2 * c) >> 1;
#pragma unroll
        for (int p = 0; p < 4; ++p) {
            const unsigned short hi = f2bf1(vv[p]);
            slab[p][o] = hi;
            slab[4 + p][o] = f2bf1(vv[p] - bf2f(hi));
        }
    }
    __syncthreads();

    const int n0 = nidx[tb];
    if (n0 < 0) return;
    const int s = spc[n0];

    bf16x8 aF[8][2];
#pragma unroll
    for (int p = 0; p < 8; ++p) {
        aF[p][0] = *(const bf16x8*)&slab[p][swz128(l15, g * 16) >> 1];
        aF[p][1] = *(const bf16x8*)&slab[p][swz128(l15, 64 + g * 16) >> 1];
    }
    __syncthreads();

    const int d = l15 + 16 * wvi;
    {
        bf16x8 bl0a = *(const bf16x8*)&WlT0[swz128(d, g * 16) >> 1];
        bf16x8 bl0b = *(const bf16x8*)&WlT0[swz128(d, 64 + g * 16) >> 1];
        bf16x8 bl1a = *(const bf16x8*)&WlT1[swz128(d, g * 16) >> 1];
        bf16x8 bl1b = *(const bf16x8*)&WlT1[swz128(d, 64 + g * 16) >> 1];
        f32x4 A0v = {0.f, 0.f, 0.f, 0.f};
        f32x4 Axv = {0.f, 0.f, 0.f, 0.f};
        f32x4 Ayv = {0.f, 0.f, 0.f, 0.f};
        f32x4 Azv = {0.f, 0.f, 0.f, 0.f};
        A0v = __builtin_amdgcn_mfma_f32_16x16x32_bf16(aF[0][0], bl0a, A0v, 0, 0, 0);
        A0v = __builtin_amdgcn_mfma_f32_16x16x32_bf16(aF[0][1], bl0b, A0v, 0, 0, 0);
        A0v = __builtin_amdgcn_mfma_f32_16x16x32_bf16(aF[4][0], bl0a, A0v, 0, 0, 0);
        A0v = __builtin_amdgcn_mfma_f32_16x16x32_bf16(aF[4][1], bl0b, A0v, 0, 0, 0);
        Axv = __builtin_amdgcn_mfma_f32_16x16x32_bf16(aF[1][0], bl1a, Axv, 0, 0, 0);
        Axv = __builtin_amdgcn_mfma_f32_16x16x32_bf16(aF[1][1], bl1b, Axv, 0, 0, 0);
        Axv = __builtin_amdgcn_mfma_f32_16x16x32_bf16(aF[5][0], bl1a, Axv, 0, 0, 0);
        Axv = __builtin_amdgcn_mfma_f32_16x16x32_bf16(aF[5][1], bl1b, Axv, 0, 0, 0);
        Ayv = __builtin_amdgcn_mfma_f32_16x16x32_bf16(aF[2][0], bl1a, Ayv, 0, 0, 0);
        Ayv = __builtin_amdgcn_mfma_f32_16x16x32_bf16(aF[2][1], bl1b, Ayv, 0, 0, 0);
        Ayv = __builtin_amdgcn_mfma_f32_16x16x32_bf16(aF[6][0], bl1a, Ayv, 0, 0, 0);
        Ayv = __builtin_amdgcn_mfma_f32_16x16x32_bf16(aF[6][1], bl1b, Ayv, 0, 0, 0);
        Azv = __builtin_amdgcn_mfma_f32_16x16x32_bf16(aF[3][0], bl1a, Azv, 0, 0, 0);
        Azv = __builtin_amdgcn_mfma_f32_16x16x32_bf16(aF[3][1], bl1b, Azv, 0, 0, 0);
        Azv = __builtin_amdgcn_mfma_f32_16x16x32_bf16(aF[7][0], bl1a, Azv, 0, 0, 0);
        Azv = __builtin_amdgcn_mfma_f32_16x16x32_bf16(aF[7][1], bl1b, Azv, 0, 0, 0);

        const float* w0p = &Wsc0[((s << 6) | d) * 5];
        const float c0 = w0p[0], c1 = w0p[1], c2 = w0p[2], c3 = w0p[3], c4 = w0p[4];
        const float4 w1v = *(const float4*)&Wsc1[((s << 6) | d) << 2];

#pragma unroll
        for (int r = 0; r < 4; ++r) {
            const float A0 = A0v[r], Ax = Axv[r], Ay = Ayv[r], Az = Azv[r];
            const float n1 = Ax * Ax + Ay * Ay + Az * Az;
            const float A0sq = A0 * A0;
            const float B0 = c0 * A0 + c1 * A0sq + c2 * A0sq * A0 + c3 * n1 + c4 * A0 * n1;
            const float gg = w1v.x + w1v.y * A0 + w1v.z * A0sq + w1v.w * n1;
            const float bb[4] = {B0, gg * Ax, gg * Ay, gg * Az};
            const int o = swz128(g * 4 + r, 2 * d) >> 1;
#pragma unroll
            for (int p = 0; p < 4; ++p) {
                const unsigned short hi = f2bf1(bb[p]);
                slab[p][o] = hi;
                slab[4 + p][o] = f2bf1(bb[p] - bf2f(hi));
            }
        }
    }
    __syncthreads();

    bf16x8 bF[8][2];
#pragma unroll
    for (int p = 0; p < 8; ++p) {
        bF[p][0] = *(const bf16x8*)&slab[p][swz128(l15, g * 16) >> 1];
        bF[p][1] = *(const bf16x8*)&slab[p][swz128(l15, 64 + g * 16) >> 1];
    }
    const int xnode = nidx[tb + l15];
    bf16x8 xF[4][2];
#pragma unroll
    for (int h = 0; h < 2; ++h) {
#pragma unroll
        for (int j = 0; j < 8; ++j) {
            const int k = h * 32 + g * 8 + j;
            float4 v = make_float4(0.f, 0.f, 0.f, 0.f);
            if (xnode >= 0) v = *(const float4*)&nf[(((size_t)xnode << 6) | k) << 2];
            xF[0][h][j] = (short)f2bf1(v.x);
            xF[1][h][j] = (short)f2bf1(v.y);
            xF[2][h][j] = (short)f2bf1(v.z);
            xF[3][h][j] = (short)f2bf1(v.w);
        }
    }

    const int ndr0 = nidx[tb + g * 4 + 0];
    const int ndr1 = nidx[tb + g * 4 + 1];
    const int ndr2 = nidx[tb + g * 4 + 2];
    const int ndr3 = nidx[tb + g * 4 + 3];

    {
        bf16x8 bp0a = *(const bf16x8*)&WpT0[swz128(d, g * 16) >> 1];
        bf16x8 bp0b = *(const bf16x8*)&WpT0[swz128(d, 64 + g * 16) >> 1];
        bf16x8 bp1a = *(const bf16x8*)&WpT1[swz128(d, g * 16) >> 1];
        bf16x8 bp1b = *(const bf16x8*)&WpT1[swz128(d, 64 + g * 16) >> 1];
        const unsigned short* wr0 = &WrT0[(size_t)s << 12];
        const unsigned short* wr1 = &WrT1[(size_t)s << 12];
        bf16x8 br0a = *(const bf16x8*)&wr0[swz128(d, g * 16) >> 1];
        bf16x8 br0b = *(const bf16x8*)&wr0[swz128(d, 64 + g * 16) >> 1];
        bf16x8 br1a = *(const bf16x8*)&wr1[swz128(d, g * 16) >> 1];
        bf16x8 br1b = *(const bf16x8*)&wr1[swz128(d, 64 + g * 16) >> 1];

        f32x4 F0v = {0.f, 0.f, 0.f, 0.f};
        f32x4 Fxv = {0.f, 0.f, 0.f, 0.f};
        f32x4 Fyv = {0.f, 0.f, 0.f, 0.f};
        f32x4 Fzv = {0.f, 0.f, 0.f, 0.f};
        F0v = __builtin_amdgcn_mfma_f32_16x16x32_bf16(bF[0][0], bp0a, F0v, 0, 0, 0);
        F0v = __builtin_amdgcn_mfma_f32_16x16x32_bf16(bF[0][1], bp0b, F0v, 0, 0, 0);
        F0v = __builtin_amdgcn_mfma_f32_16x16x32_bf16(bF[4][0], bp0a, F0v, 0, 0, 0);
        F0v = __builtin_amdgcn_mfma_f32_16x16x32_bf16(bF[4][1], bp0b, F0v, 0, 0, 0);
        F0v = __builtin_amdgcn_mfma_f32_16x16x32_bf16(xF[0][0], br0a, F0v, 0, 0, 0);
        F0v = __builtin_amdgcn_mfma_f32_16x16x32_bf16(xF[0][1], br0b, F0v, 0, 0, 0);
        Fxv = __builtin_amdgcn_mfma_f32_16x16x32_bf16(bF[1][0], bp1a, Fxv, 0, 0, 0);
        Fxv = __builtin_amdgcn_mfma_f32_16x16x32_bf16(bF[1][1], bp1b, Fxv, 0, 0, 0);
        Fxv = __builtin_amdgcn_mfma_f32_16x16x32_bf16(bF[5][0], bp1a, Fxv, 0, 0, 0);
        Fxv = __builtin_amdgcn_mfma_f32_16x16x32_bf16(bF[5][1], bp1b, Fxv, 0, 0, 0);
        Fxv = __builtin_amdgcn_mfma_f32_16x16x32_bf16(xF[1][0], br1a, Fxv, 0, 0, 0);
        Fxv = __builtin_amdgcn_mfma_f32_16x16x32_bf16(xF[1][1], br1b, Fxv, 0, 0, 0);
        Fyv = __builtin_amdgcn_mfma_f32_16x16x32_bf16(bF[2][0], bp1a, Fyv, 0, 0, 0);
        Fyv = __builtin_amdgcn_mfma_f32_16x16x32_bf16(bF[2][1], bp1b, Fyv, 0, 0, 0);
        Fyv = __builtin_amdgcn_mfma_f32_16x16x32_bf16(bF[6][0], bp1a, Fyv, 0, 0, 0);
        Fyv = __builtin_amdgcn_mfma_f32_16x16x32_bf16(bF[6][1], bp1b, Fyv, 0, 0, 0);
        Fyv = __builtin_amdgcn_mfma_f32_16x16x32_bf16(xF[2][0], br1a, Fyv, 0, 0, 0);
        Fyv = __builtin_amdgcn_mfma_f32_16x16x32_bf16(xF[2][1], br1b, Fyv, 0, 0, 0);
        Fzv = __builtin_amdgcn_mfma_f32_16x16x32_bf16(bF[3][0], bp1a, Fzv, 0, 0, 0);
        Fzv = __builtin_amdgcn_mfma_f32_16x16x32_bf16(bF[3][1], bp1b, Fzv, 0, 0, 0);
        Fzv = __builtin_amdgcn_mfma_f32_16x16x32_bf16(bF[7][0], bp1a, Fzv, 0, 0, 0);
        Fzv = __builtin_amdgcn_mfma_f32_16x16x32_bf16(bF[7][1], bp1b, Fzv, 0, 0, 0);
        Fzv = __builtin_amdgcn_mfma_f32_16x16x32_bf16(xF[3][0], br1a, Fzv, 0, 0, 0);
        Fzv = __builtin_amdgcn_mfma_f32_16x16x32_bf16(xF[3][1], br1b, Fzv, 0, 0, 0);

        const float wdv = Wrd[d];
        if (ndr0 >= 0) *(float4*)&outF[((size_t)ndr0 << 8) + (d << 2)] = make_float4(F0v[0], Fxv[0], Fyv[0], Fzv[0]);
        if (ndr1 >= 0) *(float4*)&outF[((size_t)ndr1 << 8) + (d << 2)] = make_float4(F0v[1], Fxv[1], Fyv[1], Fzv[1]);
        if (ndr2 >= 0) *(float4*)&outF[((size_t)ndr2 << 8) + (d << 2)] = make_float4(F0v[2], Fxv[2], Fyv[2], Fzv[2]);
        if (ndr3 >= 0) *(float4*)&outF[((size_t)ndr3 << 8) + (d << 2)] = make_float4(F0v[3], Fxv[3], Fyv[3], Fzv[3]);

        float ro[4] = {F0v[0] * wdv, F0v[1] * wdv, F0v[2] * wdv, F0v[3] * wdv};
#pragma unroll
        for (int mo = 1; mo < 16; mo <<= 1) {
#pragma unroll
            for (int r = 0; r < 4; ++r) ro[r] += __shfl_xor(ro[r], mo, 64);
        }
        if (l15 == 0) {
#pragma unroll
            for (int r = 0; r < 4; ++r) roS[wvi][g * 4 + r] = ro[r];
        }
    }
    __syncthreads();

    if (tid < 16) {
        const int nd = nidx[tb + tid];
        if (nd >= 0)
            out0[nd] = roS[0][tid] + roS[1][tid] + roS[2][tid] + roS[3][tid];
    }
}

// ===========================================================================
extern "C" void kernel_launch(void* const* d_in, const int* in_sizes, int n_in,
                              void* d_out, int out_size, void* d_ws, size_t ws_size,
                              hipStream_t stream)
{
    const float* edge_vectors = (const float*)d_in[0];
    const float* node_feats   = (const float*)d_in[1];
    const int*   node_species = (const int*)d_in[2];
    const float* radial       = (const float*)d_in[3];
    const int*   senders      = (const int*)d_in[4];
    const int*   receivers    = (const int*)d_in[5];
    const float* W_r1   = (const float*)d_in[6];
    const float* W_r2   = (const float*)d_in[7];
    const float* W_r3   = (const float*)d_in[8];
    const float* W_lin0 = (const float*)d_in[9];
    const float* W_lin1 = (const float*)d_in[10];
    const float* Wsc0   = (const float*)d_in[11];
    const float* Wsc1   = (const float*)d_in[12];
    const float* Wp0    = (const float*)d_in[13];
    const float* Wp1    = (const float*)d_in[14];
    const float* Wres0  = (const float*)d_in[15];
    const float* Wres1  = (const float*)d_in[16];
    const float* W_read = (const float*)d_in[17];

    float* out0 = (float*)d_out;
    float* outF = out0 + kN;

    char* ws = (char*)d_ws;
    unsigned short* m = (unsigned short*)(ws + kOffM);
    int* cnt  = (int*)(ws + kOffCnt);
    int* cnt2 = (int*)(ws + kOffCnt2);
    int* off  = (int*)(ws + kOffOff);
    int* off2 = (int*)(ws + kOffOff2);
    int* cur  = (int*)(ws + kOffCur);
    int* cur2 = (int*)(ws + kOffCur2);
    int* pos  = (int*)(ws + kOffPos);
    int* nidx = (int*)(ws + kOffNidx);
    unsigned short* WlT0 = (unsigned short*)(ws + kOffWlT0);
    unsigned short* WlT1 = (unsigned short*)(ws + kOffWlT1);
    unsigned short* WpT0 = (unsigned short*)(ws + kOffWpT0);
    unsigned short* WpT1 = (unsigned short*)(ws + kOffWpT1);
    unsigned short* WrT0 = (unsigned short*)(ws + kOffWrT0);
    unsigned short* WrT1 = (unsigned short*)(ws + kOffWrT1);

    hipMemsetAsync(cnt, 0, kN * sizeof(int) + 64, stream);
    hipMemsetAsync(nidx, 0xFF, (size_t)kTilesMax * 16 * sizeof(int), stream);

    prep_kernel<<<1024, 256, 0, stream>>>(receivers, node_species,
                                          W_lin0, W_lin1, Wp0, Wp1, Wres0, Wres1,
                                          cnt, cnt2, pos,
                                          WlT0, WlT1, WpT0, WpT1, WrT0, WrT1);
    scan_kernel<<<1, 1024, 0, stream>>>(cnt, off, cur, cnt2, off2, cur2);
    rank_kernel<<<1024, 256, 0, stream>>>(node_species, cur2, nidx);

    edge_mfma<<<256, 512, 0, stream>>>(edge_vectors, node_feats, radial,
                                       senders, receivers, off, pos,
                                       W_r1, W_r2, W_r3, m);

    node_mfma<<<kTilesMax, 256, 0, stream>>>(
        node_feats, node_species,
        WlT0, WlT1, WpT0, WpT1, WrT0, WrT1,
        Wsc0, Wsc1, W_read,
        m, off, nidx, out0, outF);
}

// Round 17
// 384.039 us; speedup vs baseline: 1.1171x; 1.0008x over previous
//
#include <hip/hip_runtime.h>

// MACE layer v17: v16 (passed, 384.3 us) + ONE change: node_mfma
// __launch_bounds__(256,2) -> (256,3): 12 waves/CU, VGPR cap ~170 (vs v13's
// failed 128-cap at (256,4)). Everything else byte-identical to v16.

typedef __attribute__((ext_vector_type(8))) short bf16x8;
typedef __attribute__((ext_vector_type(4))) float f32x4;

constexpr int kN = 50000;
constexpr int kE = 400000;
constexpr int kS = 10;
constexpr int kTilesMax = 3150;

// ws layout (bytes)
constexpr size_t kOffM    = 0;           // kE*256 ushort = 204,800,000
constexpr size_t kOffCnt  = 204800000;   // kN int
constexpr size_t kOffCnt2 = 205000000;   // 16 int
constexpr size_t kOffOff  = 205000064;   // kN+1 int
constexpr size_t kOffOff2 = 205200128;   // 16 int
constexpr size_t kOffCur  = 205200192;   // kN int
constexpr size_t kOffCur2 = 205400192;   // 16 int
constexpr size_t kOffPos  = 205400256;   // kE int (local rank within segment)
constexpr size_t kOffNidx = 207000256;   // kTilesMax*16 int
constexpr size_t kOffWlT0 = 207201856;   // 4096 ushort each
constexpr size_t kOffWlT1 = 207210048;
constexpr size_t kOffWpT0 = 207218240;
constexpr size_t kOffWpT1 = 207226432;
constexpr size_t kOffWrT0 = 207234624;   // 10*4096 ushort
constexpr size_t kOffWrT1 = 207316544;   // end 207,398,464

__device__ __forceinline__ float silu_f(float x) {
    float t = __expf(-x);
    return x / (1.0f + t);
}
// f32->bf16 round-half-away (2 ops; ties-only difference vs RNE).
// Do NOT replace with cvt_pk asm in the edge kernel (r10 NaN).
__device__ __forceinline__ unsigned short f2bf(float f) {
    return (unsigned short)((__float_as_uint(f) + 0x8000u) >> 16);
}
// cvt_pk helpers (node path only — proven there)
__device__ __forceinline__ unsigned cvt_pk_bf16(float lo, float hi) {
    unsigned r;
    asm("v_cvt_pk_bf16_f32 %0, %1, %2" : "=v"(r) : "v"(lo), "v"(hi));
    return r;
}
__device__ __forceinline__ unsigned short f2bf1(float x) {
    return (unsigned short)cvt_pk_bf16(x, 0.f);
}
__device__ __forceinline__ float bf2f(unsigned short b) {
    return __uint_as_float(((unsigned)b) << 16);
}
__device__ __forceinline__ int swz128(int row, int byteoff) {
    return row * 128 + (byteoff ^ ((row & 7) << 4));
}

// ---------------------------------------------------------------------------
// prep: edge hist stores local rank -> pos; species hist (LDS-agg); weights
// ---------------------------------------------------------------------------
__global__ __launch_bounds__(256)
void prep_kernel(const int* __restrict__ rcv, const int* __restrict__ spc,
                 const float* __restrict__ Wl0, const float* __restrict__ Wl1,
                 const float* __restrict__ Wp0, const float* __restrict__ Wp1,
                 const float* __restrict__ Wres0, const float* __restrict__ Wres1,
                 int* __restrict__ cnt, int* __restrict__ cnt2,
                 int* __restrict__ pos,
                 unsigned short* __restrict__ WlT0, unsigned short* __restrict__ WlT1,
                 unsigned short* __restrict__ WpT0, unsigned short* __restrict__ WpT1,
                 unsigned short* __restrict__ WrT0, unsigned short* __restrict__ WrT1)
{
    const int tid = threadIdx.x;
    const int gtid = blockIdx.x * 256 + tid;
    const int gstride = gridDim.x * 256;

    for (int i = gtid; i < kE; i += gstride) pos[i] = atomicAdd(&cnt[rcv[i]], 1);

    __shared__ int lh[kS];
    for (int base = blockIdx.x * 256; base < kN; base += gstride) {
        if (tid < kS) lh[tid] = 0;
        __syncthreads();
        int node = base + tid;
        if (node < kN) atomicAdd(&lh[spc[node]], 1);
        __syncthreads();
        if (tid < kS && lh[tid]) atomicAdd(&cnt2[tid], lh[tid]);
        __syncthreads();
    }

    for (int i3 = gtid; i3 < 16384 + 81920; i3 += gstride) {
        if (i3 < 16384) {
            int w = i3 >> 12, r = i3 & 4095, k = r >> 6, n = r & 63;
            const float* src = (w == 0) ? Wl0 : (w == 1) ? Wl1 : (w == 2) ? Wp0 : Wp1;
            unsigned short* dst = (w == 0) ? WlT0 : (w == 1) ? WlT1 : (w == 2) ? WpT0 : WpT1;
            dst[swz128(n, 2 * k) >> 1] = f2bf(src[r]);
        } else {
            int i4 = i3 - 16384;
            int w = i4 / 40960;
            int r5 = i4 - w * 40960;                 // s*4096 + c*64 + d
            int s = r5 >> 12, r = r5 & 4095, k = r >> 6, n = r & 63;
            const float* src = w ? Wres1 : Wres0;
            unsigned short* dst = w ? WrT1 : WrT0;
            dst[(s << 12) + (swz128(n, 2 * k) >> 1)] = f2bf(src[r5]);
        }
    }
}

// ---------------------------------------------------------------------------
__global__ __launch_bounds__(1024)
void scan_kernel(const int* __restrict__ cnt, int* __restrict__ off,
                 int* __restrict__ cur,
                 const int* __restrict__ cnt2, int* __restrict__ off2,
                 int* __restrict__ cur2)
{
    __shared__ int wred[16];
    const int tid = threadIdx.x;
    const int lane = tid & 63;
    const int wv = tid >> 6;
    const int CH = 49;
    const int b = tid * CH;
    int s = 0;
    for (int i = 0; i < CH; ++i) {
        int idx = b + i;
        if (idx < kN) s += cnt[idx];
    }
    int incl = s;
    for (int d = 1; d < 64; d <<= 1) {
        int t = __shfl_up(incl, d, 64);
        if (lane >= d) incl += t;
    }
    if (lane == 63) wred[wv] = incl;
    __syncthreads();
    if (tid < 16) {
        int o = wred[tid];
        int v = o;
        for (int d = 1; d < 16; d <<= 1) {
            int t = __shfl_up(v, d, 64);
            if (tid >= d) v += t;
        }
        wred[tid] = v - o;
    }
    __syncthreads();
    int run = wred[wv] + (incl - s);
    for (int i = 0; i < CH; ++i) {
        int idx = b + i;
        if (idx < kN) {
            int c = cnt[idx];
            off[idx] = run;
            cur[idx] = run;
            run += c;
        }
    }
    if (tid == 0) {
        off[kN] = kE;
        int base = 0;
        for (int sp = 0; sp < kS; ++sp) {
            off2[sp] = base;
            cur2[sp] = base;
            base += (cnt2[sp] + 15) & ~15;
        }
        off2[kS] = base;
    }
}

// ---------------------------------------------------------------------------
__global__ __launch_bounds__(256)
void rank_kernel(const int* __restrict__ spc,
                 int* __restrict__ cur2, int* __restrict__ nidx)
{
    const int tid = threadIdx.x;
    const int gstride = gridDim.x * 256;

    __shared__ int lh[kS];
    __shared__ int gbase[kS];
    for (int base = blockIdx.x * 256; base < kN; base += gstride) {
        if (tid < kS) lh[tid] = 0;
        __syncthreads();
        const int node = base + tid;
        int s = -1, lr = 0;
        if (node < kN) {
            s = spc[node];
            lr = atomicAdd(&lh[s], 1);
        }
        __syncthreads();
        if (tid < kS) gbase[tid] = lh[tid] ? atomicAdd(&cur2[tid], lh[tid]) : 0;
        __syncthreads();
        if (node < kN) nidx[gbase[s] + lr] = node;
        __syncthreads();
    }
}

// ---------------------------------------------------------------------------
// edge_mfma (v16, unchanged). 512 thr (8 waves), 16 edges/wave.
// ---------------------------------------------------------------------------
__global__ __launch_bounds__(512, 1)
void edge_mfma(const float* __restrict__ ev,
               const float* __restrict__ nf,
               const float* __restrict__ rad,
               const int* __restrict__ snd,
               const int* __restrict__ rcv,
               const int* __restrict__ off,
               const int* __restrict__ pos,
               const float* __restrict__ W1,
               const float* __restrict__ W2,
               const float* __restrict__ W3,
               unsigned short* __restrict__ mq)
{
    __shared__ unsigned short W2T[64 * 64];
    __shared__ unsigned short W3T[256 * 64];
    __shared__ unsigned short h1s[8][16 * 64];
    __shared__ unsigned short h2s[8][16 * 64];
    __shared__ unsigned short wTs[8][256 * 20];

    const int tid = threadIdx.x;
    for (int i = tid; i < 64 * 64; i += 512) {
        int k = i >> 6, n = i & 63;
        W2T[swz128(n, 2 * k) >> 1] = f2bf(W2[i]);
    }
    for (int i = tid; i < 256 * 64; i += 512) {
        int k = i >> 8, n = i & 255;
        W3T[swz128(n, 2 * k) >> 1] = f2bf(W3[i]);
    }
    __syncthreads();

    const int lane = tid & 63;
    const int wvi = tid >> 6;
    const int l15 = lane & 15;
    const int g = lane >> 4;

    float w1r[8];
#pragma unroll
    for (int r = 0; r < 8; ++r) w1r[r] = W1[(r << 6) | lane];

    unsigned short* h1w = h1s[wvi];
    unsigned short* h2w = h2s[wvi];
    unsigned short* wTw = wTs[wvi];

    for (int t = blockIdx.x; t < kE / 128; t += gridDim.x) {
        const int et = t * 128 + wvi * 16;

        // per-lane edge scalars for edge et + l15 (broadcast in Phase D)
        const int eidL = et + l15;
        const int sidL = snd[eidL];
        const int pL = off[rcv[eidL]] + pos[eidL];
        const float exL = ev[(size_t)eidL * 3 + 0];
        const float eyL = ev[(size_t)eidL * 3 + 1];
        const float ezL = ev[(size_t)eidL * 3 + 2];
        const float riL = rsqrtf(exL * exL + eyL * eyL + ezL * ezL + 1e-12f);
        const float y0L = 1.7320508075688772f * exL * riL;
        const float y1L = 1.7320508075688772f * eyL * riL;
        const float y2L = 1.7320508075688772f * ezL * riL;

        for (int e = 0; e < 16; ++e) {
            const float4 ra = *(const float4*)&rad[(size_t)(et + e) * 8];
            const float4 rb = *(const float4*)&rad[(size_t)(et + e) * 8 + 4];
            float acc = ra.x * w1r[0] + ra.y * w1r[1] + ra.z * w1r[2] + ra.w * w1r[3]
                      + rb.x * w1r[4] + rb.y * w1r[5] + rb.z * w1r[6] + rb.w * w1r[7];
            h1w[swz128(e, 2 * lane) >> 1] = f2bf(silu_f(acc));
        }
        __builtin_amdgcn_wave_barrier();

        bf16x8 a0 = *(const bf16x8*)&h1w[swz128(l15, g * 16) >> 1];
        bf16x8 a1 = *(const bf16x8*)&h1w[swz128(l15, 64 + g * 16) >> 1];

#pragma unroll
        for (int n0 = 0; n0 < 64; n0 += 16) {
            const int n = n0 + l15;
            bf16x8 b0 = *(const bf16x8*)&W2T[swz128(n, g * 16) >> 1];
            bf16x8 b1 = *(const bf16x8*)&W2T[swz128(n, 64 + g * 16) >> 1];
            f32x4 acc = {0.f, 0.f, 0.f, 0.f};
            acc = __builtin_amdgcn_mfma_f32_16x16x32_bf16(a0, b0, acc, 0, 0, 0);
            acc = __builtin_amdgcn_mfma_f32_16x16x32_bf16(a1, b1, acc, 0, 0, 0);
#pragma unroll
            for (int r = 0; r < 4; ++r) {
                int e2 = g * 4 + r;
                h2w[swz128(e2, 2 * n) >> 1] = f2bf(silu_f(acc[r]));
            }
        }
        __builtin_amdgcn_wave_barrier();

        bf16x8 c0 = *(const bf16x8*)&h2w[swz128(l15, g * 16) >> 1];
        bf16x8 c1 = *(const bf16x8*)&h2w[swz128(l15, 64 + g * 16) >> 1];
#pragma unroll
        for (int m0 = 0; m0 < 16; ++m0) {
            const int nrow = m0 * 16 + l15;
            bf16x8 wa0 = *(const bf16x8*)&W3T[swz128(nrow, g * 16) >> 1];
            bf16x8 wa1 = *(const bf16x8*)&W3T[swz128(nrow, 64 + g * 16) >> 1];
            f32x4 acc = {0.f, 0.f, 0.f, 0.f};
            acc = __builtin_amdgcn_mfma_f32_16x16x32_bf16(wa0, c0, acc, 0, 0, 0);
            acc = __builtin_amdgcn_mfma_f32_16x16x32_bf16(wa1, c1, acc, 0, 0, 0);
#pragma unroll
            for (int r = 0; r < 4; ++r) {
                int nn = m0 * 16 + g * 4 + r;
                wTw[nn * 20 + l15] = f2bf(acc[r]);
            }
        }
        __builtin_amdgcn_wave_barrier();

        const int c = lane;
#pragma unroll
        for (int grp = 0; grp < 4; ++grp) {
            ushort4 qa[4];
#pragma unroll
            for (int k = 0; k < 4; ++k)
                qa[k] = *(const ushort4*)&wTw[(k * 64 + c) * 20 + grp * 4];
            const unsigned short* qp = (const unsigned short*)qa;
#pragma unroll
            for (int e = 0; e < 4; ++e) {
                const int idx = grp * 4 + e;
                const int sid = __shfl(sidL, idx, 64);
                const int p = __shfl(pL, idx, 64);
                const float y0 = __shfl(y0L, idx, 64);
                const float y1 = __shfl(y1L, idx, 64);
                const float y2 = __shfl(y2L, idx, 64);
                const float4 xv = *(const float4*)&nf[(((size_t)sid << 6) | c) << 2];
                const float w0 = bf2f(qp[0 * 4 + e]);
                const float w1 = bf2f(qp[1 * 4 + e]);
                const float w2v = bf2f(qp[2 * 4 + e]);
                const float w3v = bf2f(qp[3 * 4 + e]);
                const float dot1 = xv.y * y0 + xv.z * y1 + xv.w * y2;
                const float m0v = w0 * xv.x + w1 * dot1;
                const float t2 = w2v * xv.x;
                ushort4 q;
                q.x = f2bf(m0v);
                q.y = f2bf(t2 * y0 + w3v * xv.y);
                q.z = f2bf(t2 * y1 + w3v * xv.z);
                q.w = f2bf(t2 * y2 + w3v * xv.w);
                *(ushort4*)&mq[((size_t)p << 8) + (c << 2)] = q;
            }
        }
        __builtin_amdgcn_wave_barrier();
    }
}

// ---------------------------------------------------------------------------
// node_mfma (v16 + launch_bounds (256,3)): block (4 waves) per 16-node tile;
// hi/lo slab, 8-deep gather ILP.
// ---------------------------------------------------------------------------
__global__ __launch_bounds__(256, 3)
void node_mfma(const float* __restrict__ nf, const int* __restrict__ spc,
               const unsigned short* __restrict__ WlT0, const unsigned short* __restrict__ WlT1,
               const unsigned short* __restrict__ WpT0, const unsigned short* __restrict__ WpT1,
               const unsigned short* __restrict__ WrT0, const unsigned short* __restrict__ WrT1,
               const float* __restrict__ Wsc0, const float* __restrict__ Wsc1,
               const float* __restrict__ Wrd,
               const unsigned short* __restrict__ m, const int* __restrict__ off,
               const int* __restrict__ nidx,
               float* __restrict__ out0, float* __restrict__ outF)
{
    __shared__ unsigned short slab[8][1024];   // planes 0-3 hi, 4-7 lo (16 KB)
    __shared__ float roS[4][16];

    const int tid = threadIdx.x;
    const int lane = tid & 63;
    const int wvi = tid >> 6;
    const int l15 = lane & 15;
    const int g = lane >> 4;
    const int tb = (int)blockIdx.x << 4;

    const int c = lane;
    for (int e4 = 0; e4 < 4; ++e4) {
        const int e = wvi * 4 + e4;
        const int node = nidx[tb + e];
        float ax = 0.f, ay = 0.f, az = 0.f, aw = 0.f;
        if (node >= 0) {
            const int beg = off[node], end = off[node + 1];
            int i = beg;
            for (; i + 8 <= end; i += 8) {
                const ushort4 q0 = *(const ushort4*)&m[((size_t)(i + 0) << 8) + (c << 2)];
                const ushort4 q1 = *(const ushort4*)&m[((size_t)(i + 1) << 8) + (c << 2)];
                const ushort4 q2 = *(const ushort4*)&m[((size_t)(i + 2) << 8) + (c << 2)];
                const ushort4 q3 = *(const ushort4*)&m[((size_t)(i + 3) << 8) + (c << 2)];
                const ushort4 q4 = *(const ushort4*)&m[((size_t)(i + 4) << 8) + (c << 2)];
                const ushort4 q5 = *(const ushort4*)&m[((size_t)(i + 5) << 8) + (c << 2)];
                const ushort4 q6 = *(const ushort4*)&m[((size_t)(i + 6) << 8) + (c << 2)];
                const ushort4 q7 = *(const ushort4*)&m[((size_t)(i + 7) << 8) + (c << 2)];
                ax += ((bf2f(q0.x) + bf2f(q1.x)) + (bf2f(q2.x) + bf2f(q3.x)))
                    + ((bf2f(q4.x) + bf2f(q5.x)) + (bf2f(q6.x) + bf2f(q7.x)));
                ay += ((bf2f(q0.y) + bf2f(q1.y)) + (bf2f(q2.y) + bf2f(q3.y)))
                    + ((bf2f(q4.y) + bf2f(q5.y)) + (bf2f(q6.y) + bf2f(q7.y)));
                az += ((bf2f(q0.z) + bf2f(q1.z)) + (bf2f(q2.z) + bf2f(q3.z)))
                    + ((bf2f(q4.z) + bf2f(q5.z)) + (bf2f(q6.z) + bf2f(q7.z)));
                aw += ((bf2f(q0.w) + bf2f(q1.w)) + (bf2f(q2.w) + bf2f(q3.w)))
                    + ((bf2f(q4.w) + bf2f(q5.w)) + (bf2f(q6.w) + bf2f(q7.w)));
            }
            for (; i + 4 <= end; i += 4) {
                const ushort4 q0 = *(const ushort4*)&m[((size_t)(i + 0) << 8) + (c << 2)];
                const ushort4 q1 = *(const ushort4*)&m[((size_t)(i + 1) << 8) + (c << 2)];
                const ushort4 q2 = *(const ushort4*)&m[((size_t)(i + 2) << 8) + (c << 2)];
                const ushort4 q3 = *(const ushort4*)&m[((size_t)(i + 3) << 8) + (c << 2)];
                ax += (bf2f(q0.x) + bf2f(q1.x)) + (bf2f(q2.x) + bf2f(q3.x));
                ay += (bf2f(q0.y) + bf2f(q1.y)) + (bf2f(q2.y) + bf2f(q3.y));
                az += (bf2f(q0.z) + bf2f(q1.z)) + (bf2f(q2.z) + bf2f(q3.z));
                aw += (bf2f(q0.w) + bf2f(q1.w)) + (bf2f(q2.w) + bf2f(q3.w));
            }
            for (; i < end; ++i) {
                const ushort4 q = *(const ushort4*)&m[((size_t)i << 8) + (c << 2)];
                ax += bf2f(q.x); ay += bf2f(q.y); az += bf2f(q.z); aw += bf2f(q.w);
            }
        }
        const float vv[4] = {ax * 0.125f, ay * 0.125f, az * 0.125f, aw * 0.125f};
        const int o = swz128(e, 2 * c) >> 1;
#pragma unroll
        for (int p = 0; p < 4; ++p) {
            const unsigned short hi = f2bf1(vv[p]);
            slab[p][o] = hi;
            slab[4 + p][o] = f2bf1(vv[p] - bf2f(hi));
        }
    }
    __syncthreads();

    const int n0 = nidx[tb];
    if (n0 < 0) return;
    const int s = spc[n0];

    bf16x8 aF[8][2];
#pragma unroll
    for (int p = 0; p < 8; ++p) {
        aF[p][0] = *(const bf16x8*)&slab[p][swz128(l15, g * 16) >> 1];
        aF[p][1] = *(const bf16x8*)&slab[p][swz128(l15, 64 + g * 16) >> 1];
    }
    __syncthreads();

    const int d = l15 + 16 * wvi;
    {
        bf16x8 bl0a = *(const bf16x8*)&WlT0[swz128(d, g * 16) >> 1];
        bf16x8 bl0b = *(const bf16x8*)&WlT0[swz128(d, 64 + g * 16) >> 1];
        bf16x8 bl1a = *(const bf16x8*)&WlT1[swz128(d, g * 16) >> 1];
        bf16x8 bl1b = *(const bf16x8*)&WlT1[swz128(d, 64 + g * 16) >> 1];
        f32x4 A0v = {0.f, 0.f, 0.f, 0.f};
        f32x4 Axv = {0.f, 0.f, 0.f, 0.f};
        f32x4 Ayv = {0.f, 0.f, 0.f, 0.f};
        f32x4 Azv = {0.f, 0.f, 0.f, 0.f};
        A0v = __builtin_amdgcn_mfma_f32_16x16x32_bf16(aF[0][0], bl0a, A0v, 0, 0, 0);
        A0v = __builtin_amdgcn_mfma_f32_16x16x32_bf16(aF[0][1], bl0b, A0v, 0, 0, 0);
        A0v = __builtin_amdgcn_mfma_f32_16x16x32_bf16(aF[4][0], bl0a, A0v, 0, 0, 0);
        A0v = __builtin_amdgcn_mfma_f32_16x16x32_bf16(aF[4][1], bl0b, A0v, 0, 0, 0);
        Axv = __builtin_amdgcn_mfma_f32_16x16x32_bf16(aF[1][0], bl1a, Axv, 0, 0, 0);
        Axv = __builtin_amdgcn_mfma_f32_16x16x32_bf16(aF[1][1], bl1b, Axv, 0, 0, 0);
        Axv = __builtin_amdgcn_mfma_f32_16x16x32_bf16(aF[5][0], bl1a, Axv, 0, 0, 0);
        Axv = __builtin_amdgcn_mfma_f32_16x16x32_bf16(aF[5][1], bl1b, Axv, 0, 0, 0);
        Ayv = __builtin_amdgcn_mfma_f32_16x16x32_bf16(aF[2][0], bl1a, Ayv, 0, 0, 0);
        Ayv = __builtin_amdgcn_mfma_f32_16x16x32_bf16(aF[2][1], bl1b, Ayv, 0, 0, 0);
        Ayv = __builtin_amdgcn_mfma_f32_16x16x32_bf16(aF[6][0], bl1a, Ayv, 0, 0, 0);
        Ayv = __builtin_amdgcn_mfma_f32_16x16x32_bf16(aF[6][1], bl1b, Ayv, 0, 0, 0);
        Azv = __builtin_amdgcn_mfma_f32_16x16x32_bf16(aF[3][0], bl1a, Azv, 0, 0, 0);
        Azv = __builtin_amdgcn_mfma_f32_16x16x32_bf16(aF[3][1], bl1b, Azv, 0, 0, 0);
        Azv = __builtin_amdgcn_mfma_f32_16x16x32_bf16(aF[7][0], bl1a, Azv, 0, 0, 0);
        Azv = __builtin_amdgcn_mfma_f32_16x16x32_bf16(aF[7][1], bl1b, Azv, 0, 0, 0);

        const float* w0p = &Wsc0[((s << 6) | d) * 5];
        const float c0 = w0p[0], c1 = w0p[1], c2 = w0p[2], c3 = w0p[3], c4 = w0p[4];
        const float4 w1v = *(const float4*)&Wsc1[((s << 6) | d) << 2];

#pragma unroll
        for (int r = 0; r < 4; ++r) {
            const float A0 = A0v[r], Ax = Axv[r], Ay = Ayv[r], Az = Azv[r];
            const float n1 = Ax * Ax + Ay * Ay + Az * Az;
            const float A0sq = A0 * A0;
            const float B0 = c0 * A0 + c1 * A0sq + c2 * A0sq * A0 + c3 * n1 + c4 * A0 * n1;
            const float gg = w1v.x + w1v.y * A0 + w1v.z * A0sq + w1v.w * n1;
            const float bb[4] = {B0, gg * Ax, gg * Ay, gg * Az};
            const int o = swz128(g * 4 + r, 2 * d) >> 1;
#pragma unroll
            for (int p = 0; p < 4; ++p) {
                const unsigned short hi = f2bf1(bb[p]);
                slab[p][o] = hi;
                slab[4 + p][o] = f2bf1(bb[p] - bf2f(hi));
            }
        }
    }
    __syncthreads();

    bf16x8 bF[8][2];
#pragma unroll
    for (int p = 0; p < 8; ++p) {
        bF[p][0] = *(const bf16x8*)&slab[p][swz128(l15, g * 16) >> 1];
        bF[p][1] = *(const bf16x8*)&slab[p][swz128(l15, 64 + g * 16) >> 1];
    }
    const int xnode = nidx[tb + l15];
    bf16x8 xF[4][2];
#pragma unroll
    for (int h = 0; h < 2; ++h) {
#pragma unroll
        for (int j = 0; j < 8; ++j) {
            const int k = h * 32 + g * 8 + j;
            float4 v = make_float4(0.f, 0.f, 0.f, 0.f);
            if (xnode >= 0) v = *(const float4*)&nf[(((size_t)xnode << 6) | k) << 2];
            xF[0][h][j] = (short)f2bf1(v.x);
            xF[1][h][j] = (short)f2bf1(v.y);
            xF[2][h][j] = (short)f2bf1(v.z);
            xF[3][h][j] = (short)f2bf1(v.w);
        }
    }

    const int ndr0 = nidx[tb + g * 4 + 0];
    const int ndr1 = nidx[tb + g * 4 + 1];
    const int ndr2 = nidx[tb + g * 4 + 2];
    const int ndr3 = nidx[tb + g * 4 + 3];

    {
        bf16x8 bp0a = *(const bf16x8*)&WpT0[swz128(d, g * 16) >> 1];
        bf16x8 bp0b = *(const bf16x8*)&WpT0[swz128(d, 64 + g * 16) >> 1];
        bf16x8 bp1a = *(const bf16x8*)&WpT1[swz128(d, g * 16) >> 1];
        bf16x8 bp1b = *(const bf16x8*)&WpT1[swz128(d, 64 + g * 16) >> 1];
        const unsigned short* wr0 = &WrT0[(size_t)s << 12];
        const unsigned short* wr1 = &WrT1[(size_t)s << 12];
        bf16x8 br0a = *(const bf16x8*)&wr0[swz128(d, g * 16) >> 1];
        bf16x8 br0b = *(const bf16x8*)&wr0[swz128(d, 64 + g * 16) >> 1];
        bf16x8 br1a = *(const bf16x8*)&wr1[swz128(d, g * 16) >> 1];
        bf16x8 br1b = *(const bf16x8*)&wr1[swz128(d, 64 + g * 16) >> 1];

        f32x4 F0v = {0.f, 0.f, 0.f, 0.f};
        f32x4 Fxv = {0.f, 0.f, 0.f, 0.f};
        f32x4 Fyv = {0.f, 0.f, 0.f, 0.f};
        f32x4 Fzv = {0.f, 0.f, 0.f, 0.f};
        F0v = __builtin_amdgcn_mfma_f32_16x16x32_bf16(bF[0][0], bp0a, F0v, 0, 0, 0);
        F0v = __builtin_amdgcn_mfma_f32_16x16x32_bf16(bF[0][1], bp0b, F0v, 0, 0, 0);
        F0v = __builtin_amdgcn_mfma_f32_16x16x32_bf16(bF[4][0], bp0a, F0v, 0, 0, 0);
        F0v = __builtin_amdgcn_mfma_f32_16x16x32_bf16(bF[4][1], bp0b, F0v, 0, 0, 0);
        F0v = __builtin_amdgcn_mfma_f32_16x16x32_bf16(xF[0][0], br0a, F0v, 0, 0, 0);
        F0v = __builtin_amdgcn_mfma_f32_16x16x32_bf16(xF[0][1], br0b, F0v, 0, 0, 0);
        Fxv = __builtin_amdgcn_mfma_f32_16x16x32_bf16(bF[1][0], bp1a, Fxv, 0, 0, 0);
        Fxv = __builtin_amdgcn_mfma_f32_16x16x32_bf16(bF[1][1], bp1b, Fxv, 0, 0, 0);
        Fxv = __builtin_amdgcn_mfma_f32_16x16x32_bf16(bF[5][0], bp1a, Fxv, 0, 0, 0);
        Fxv = __builtin_amdgcn_mfma_f32_16x16x32_bf16(bF[5][1], bp1b, Fxv, 0, 0, 0);
        Fxv = __builtin_amdgcn_mfma_f32_16x16x32_bf16(xF[1][0], br1a, Fxv, 0, 0, 0);
        Fxv = __builtin_amdgcn_mfma_f32_16x16x32_bf16(xF[1][1], br1b, Fxv, 0, 0, 0);
        Fyv = __builtin_amdgcn_mfma_f32_16x16x32_bf16(bF[2][0], bp1a, Fyv, 0, 0, 0);
        Fyv = __builtin_amdgcn_mfma_f32_16x16x32_bf16(bF[2][1], bp1b, Fyv, 0, 0, 0);
        Fyv = __builtin_amdgcn_mfma_f32_16x16x32_bf16(bF[6][0], bp1a, Fyv, 0, 0, 0);
        Fyv = __builtin_amdgcn_mfma_f32_16x16x32_bf16(bF[6][1], bp1b, Fyv, 0, 0, 0);
        Fyv = __builtin_amdgcn_mfma_f32_16x16x32_bf16(xF[2][0], br1a, Fyv, 0, 0, 0);
        Fyv = __builtin_amdgcn_mfma_f32_16x16x32_bf16(xF[2][1], br1b, Fyv, 0, 0, 0);
        Fzv = __builtin_amdgcn_mfma_f32_16x16x32_bf16(bF[3][0], bp1a, Fzv, 0, 0, 0);
        Fzv = __builtin_amdgcn_mfma_f32_16x16x32_bf16(bF[3][1], bp1b, Fzv, 0, 0, 0);
        Fzv = __builtin_amdgcn_mfma_f32_16x16x32_bf16(bF[7][0], bp1a, Fzv, 0, 0, 0);
        Fzv = __builtin_amdgcn_mfma_f32_16x16x32_bf16(bF[7][1], bp1b, Fzv, 0, 0, 0);
        Fzv = __builtin_amdgcn_mfma_f32_16x16x32_bf16(xF[3][0], br1a, Fzv, 0, 0, 0);
        Fzv = __builtin_amdgcn_mfma_f32_16x16x32_bf16(xF[3][1], br1b, Fzv, 0, 0, 0);

        const float wdv = Wrd[d];
        if (ndr0 >= 0) *(float4*)&outF[((size_t)ndr0 << 8) + (d << 2)] = make_float4(F0v[0], Fxv[0], Fyv[0], Fzv[0]);
        if (ndr1 >= 0) *(float4*)&outF[((size_t)ndr1 << 8) + (d << 2)] = make_float4(F0v[1], Fxv[1], Fyv[1], Fzv[1]);
        if (ndr2 >= 0) *(float4*)&outF[((size_t)ndr2 << 8) + (d << 2)] = make_float4(F0v[2], Fxv[2], Fyv[2], Fzv[2]);
        if (ndr3 >= 0) *(float4*)&outF[((size_t)ndr3 << 8) + (d << 2)] = make_float4(F0v[3], Fxv[3], Fyv[3], Fzv[3]);

        float ro[4] = {F0v[0] * wdv, F0v[1] * wdv, F0v[2] * wdv, F0v[3] * wdv};
#pragma unroll
        for (int mo = 1; mo < 16; mo <<= 1) {
#pragma unroll
            for (int r = 0; r < 4; ++r) ro[r] += __shfl_xor(ro[r], mo, 64);
        }
        if (l15 == 0) {
#pragma unroll
            for (int r = 0; r < 4; ++r) roS[wvi][g * 4 + r] = ro[r];
        }
    }
    __syncthreads();

    if (tid < 16) {
        const int nd = nidx[tb + tid];
        if (nd >= 0)
            out0[nd] = roS[0][tid] + roS[1][tid] + roS[2][tid] + roS[3][tid];
    }
}

// ===========================================================================
extern "C" void kernel_launch(void* const* d_in, const int* in_sizes, int n_in,
                              void* d_out, int out_size, void* d_ws, size_t ws_size,
                              hipStream_t stream)
{
    const float* edge_vectors = (const float*)d_in[0];
    const float* node_feats   = (const float*)d_in[1];
    const int*   node_species = (const int*)d_in[2];
    const float* radial       = (const float*)d_in[3];
    const int*   senders      = (const int*)d_in[4];
    const int*   receivers    = (const int*)d_in[5];
    const float* W_r1   = (const float*)d_in[6];
    const float* W_r2   = (const float*)d_in[7];
    const float* W_r3   = (const float*)d_in[8];
    const float* W_lin0 = (const float*)d_in[9];
    const float* W_lin1 = (const float*)d_in[10];
    const float* Wsc0   = (const float*)d_in[11];
    const float* Wsc1   = (const float*)d_in[12];
    const float* Wp0    = (const float*)d_in[13];
    const float* Wp1    = (const float*)d_in[14];
    const float* Wres0  = (const float*)d_in[15];
    const float* Wres1  = (const float*)d_in[16];
    const float* W_read = (const float*)d_in[17];

    float* out0 = (float*)d_out;
    float* outF = out0 + kN;

    char* ws = (char*)d_ws;
    unsigned short* m = (unsigned short*)(ws + kOffM);
    int* cnt  = (int*)(ws + kOffCnt);
    int* cnt2 = (int*)(ws + kOffCnt2);
    int* off  = (int*)(ws + kOffOff);
    int* off2 = (int*)(ws + kOffOff2);
    int* cur  = (int*)(ws + kOffCur);
    int* cur2 = (int*)(ws + kOffCur2);
    int* pos  = (int*)(ws + kOffPos);
    int* nidx = (int*)(ws + kOffNidx);
    unsigned short* WlT0 = (unsigned short*)(ws + kOffWlT0);
    unsigned short* WlT1 = (unsigned short*)(ws + kOffWlT1);
    unsigned short* WpT0 = (unsigned short*)(ws + kOffWpT0);
    unsigned short* WpT1 = (unsigned short*)(ws + kOffWpT1);
    unsigned short* WrT0 = (unsigned short*)(ws + kOffWrT0);
    unsigned short* WrT1 = (unsigned short*)(ws + kOffWrT1);

    hipMemsetAsync(cnt, 0, kN * sizeof(int) + 64, stream);
    hipMemsetAsync(nidx, 0xFF, (size_t)kTilesMax * 16 * sizeof(int), stream);

    prep_kernel<<<1024, 256, 0, stream>>>(receivers, node_species,
                                          W_lin0, W_lin1, Wp0, Wp1, Wres0, Wres1,
                                          cnt, cnt2, pos,
                                          WlT0, WlT1, WpT0, WpT1, WrT0, WrT1);
    scan_kernel<<<1, 1024, 0, stream>>>(cnt, off, cur, cnt2, off2, cur2);
    rank_kernel<<<1024, 256, 0, stream>>>(node_species, cur2, nidx);

    edge_mfma<<<256, 512, 0, stream>>>(edge_vectors, node_feats, radial,
                                       senders, receivers, off, pos,
                                       W_r1, W_r2, W_r3, m);

    node_mfma<<<kTilesMax, 256, 0, stream>>>(
        node_feats, node_species,
        WlT0, WlT1, WpT0, WpT1, WrT0, WrT1,
        Wsc0, Wsc1, W_read,
        m, off, nidx, out0, outF);
}